// Round 12
// baseline (253.371 us; speedup 1.0000x reference)
//
#include <hip/hip_runtime.h>
#include <stdint.h>

// Pipeline: kx_ln | k_gemm_q (256x256 4-phase counted-vmcnt) + k_gemm_kv
// (m97 128x128) | k_attn (no-max pipeline, q pre-scaled) | k_out_fused.
// x[4,64,256,512]; heads=8, dhead=64.

#define DIM   512
#define DHEAD 64
#define RLEN  256
#define TOK   65536

typedef __bf16 bf16;
typedef __bf16 bf16x4 __attribute__((ext_vector_type(4)));
typedef __bf16 bf16x8 __attribute__((ext_vector_type(8)));
typedef float  f32x4  __attribute__((ext_vector_type(4)));
typedef short  s16x4  __attribute__((ext_vector_type(4)));

__device__ __forceinline__ f32x4 mfma16(bf16x8 a, bf16x8 b, f32x4 c) {
  return __builtin_amdgcn_mfma_f32_16x16x32_bf16(a, b, c, 0, 0, 0);
}
__device__ __forceinline__ f32x4 mfma_k16(bf16x4 a, bf16x4 b, f32x4 c) {
#if __has_builtin(__builtin_amdgcn_mfma_f32_16x16x16bf16_1k)
  return __builtin_amdgcn_mfma_f32_16x16x16bf16_1k(
      __builtin_bit_cast(s16x4, a), __builtin_bit_cast(s16x4, b), c, 0, 0, 0);
#else
  f32x4 d = c;
  asm volatile("v_mfma_f32_16x16x16_bf16 %0, %1, %2, %0"
               : "+v"(d) : "v"(a), "v"(b));
  return d;
#endif
}
__device__ __forceinline__ f32x4 fzero4() {
  f32x4 z; z[0] = z[1] = z[2] = z[3] = 0.f; return z;
}
__device__ __forceinline__ void gload_lds16(const void* g, void* l) {
  __builtin_amdgcn_global_load_lds(
      (const __attribute__((address_space(1))) void*)g,
      (__attribute__((address_space(3))) void*)l, 16, 0, 0);
}

// ---------------- K0: weights -> bf16, [n][k] layout ----------------
__global__ __launch_bounds__(256) void k_prep(
    const float* __restrict__ Wq, const float* __restrict__ Wkv,
    const float* __restrict__ Wout,
    bf16* __restrict__ wall, bf16* __restrict__ woutt) {
  int t = blockIdx.x * 256 + threadIdx.x;   // grid covers 640*512
  int n = t >> 9, k = t & 511;
  float v = (n < DIM) ? Wq[k * DIM + n] : Wkv[k * 128 + (n - DIM)];
  wall[t] = (bf16)v;
  if (t < DIM * DIM) woutt[t] = (bf16)Wout[k * DIM + n];
}

// ---------------- kx_ln: LayerNorm(x)*g -> bf16 ----------------
__global__ __launch_bounds__(256) void kx_ln(
    const float* __restrict__ x, const float* __restrict__ gnorm,
    bf16* __restrict__ xn) {
  const int lane = threadIdx.x & 63;
  const int gw = blockIdx.x * 4 + (threadIdx.x >> 6);
  float gv[8];
  #pragma unroll
  for (int j = 0; j < 8; ++j) gv[j] = gnorm[lane * 8 + j];
  #pragma unroll
  for (int i = 0; i < 8; ++i) {
    size_t row = (size_t)gw * 8 + i;
    const float4* xp = (const float4*)(x + row * DIM + lane * 8);
    float4 v0 = xp[0], v1 = xp[1];
    float s  = v0.x + v0.y + v0.z + v0.w + v1.x + v1.y + v1.z + v1.w;
    float sq = v0.x*v0.x + v0.y*v0.y + v0.z*v0.z + v0.w*v0.w
             + v1.x*v1.x + v1.y*v1.y + v1.z*v1.z + v1.w*v1.w;
    #pragma unroll
    for (int d = 1; d < 64; d <<= 1) { s += __shfl_xor(s, d); sq += __shfl_xor(sq, d); }
    float mean = s * (1.f / 512.f);
    float var  = sq * (1.f / 512.f) - mean * mean;
    float rs   = rsqrtf(var + 1e-5f);
    bf16x8 o;
    o[0] = (bf16)((v0.x - mean) * rs * gv[0]);
    o[1] = (bf16)((v0.y - mean) * rs * gv[1]);
    o[2] = (bf16)((v0.z - mean) * rs * gv[2]);
    o[3] = (bf16)((v0.w - mean) * rs * gv[3]);
    o[4] = (bf16)((v1.x - mean) * rs * gv[4]);
    o[5] = (bf16)((v1.y - mean) * rs * gv[5]);
    o[6] = (bf16)((v1.z - mean) * rs * gv[6]);
    o[7] = (bf16)((v1.w - mean) * rs * gv[7]);
    *(bf16x8*)(xn + row * DIM + lane * 8) = o;
  }
}

// ---------------- k_gemm_q: 256x256 tile, 4-phase counted-vmcnt ------------
// q[M,512] = xn @ Wq^T, output pre-scaled by 0.125*log2(e) (attn folds it).
// 512 thr / 8 waves (2m x 4n), per-wave 128x64. BK=64, 8 K-tiles, dbuf LDS
// 128 KB. Per phase: ds_read frags | issue gload_lds (ph 0-1) | s_barrier |
// setprio(1) 16 MFMA setprio(0) | [ph3: vmcnt drain of next-tile loads] |
// s_barrier. Loads stay in flight across barriers (T3+T4); T5 setprio.
__global__ __launch_bounds__(512) void k_gemm_q(
    const bf16* __restrict__ xn, const bf16* __restrict__ wall,
    bf16* __restrict__ qbuf) {
  __shared__ bf16 sa[2][256 * 64];   // 2 x 32 KB
  __shared__ bf16 sb[2][256 * 64];   // 2 x 32 KB
  const int t = threadIdx.x, wave = t >> 6, lane = t & 63;
  const int l15 = lane & 15, g = lane >> 4;
  const int wm = wave >> 2, wn = wave & 3;
  int wg = (blockIdx.x & 7) * 64 + (blockIdx.x >> 3);   // nwg=512=8*64
  const int bm = wg >> 1, bn = wg & 1;                  // bn inner: A L2 reuse
  const char* Abase = (const char*)(xn   + (size_t)bm * 256 * DIM);
  const char* Bbase = (const char*)(wall + (size_t)bn * 256 * DIM);

  // prologue: stage K-tile 0 (A,B: 4 chunks each per thread)
  #pragma unroll
  for (int i = 0; i < 4; ++i) {
    int chunk = i * 512 + t;                 // 16B chunk over [256 rows][8 units]
    int row = chunk >> 3, unit = chunk & 7;
    int so = row * 1024 + ((unit ^ (row & 7)) << 4);
    gload_lds16(Abase + so, (char*)&sa[0][0] + i * 8192 + wave * 1024);
    gload_lds16(Bbase + so, (char*)&sb[0][0] + i * 8192 + wave * 1024);
  }
  f32x4 acc[8][4];
  #pragma unroll
  for (int mi = 0; mi < 8; ++mi)
    #pragma unroll
    for (int ni = 0; ni < 4; ++ni) acc[mi][ni] = fzero4();
  __syncthreads();   // drains prologue loads

  for (int tt = 0; tt < 8; ++tt) {
    const int cur = tt & 1;
    const char* sac = (const char*)&sa[cur][0];
    const char* sbc = (const char*)&sb[cur][0];
    char* san = (char*)&sa[cur ^ 1][0];
    char* sbn = (char*)&sb[cur ^ 1][0];
    bf16x8 bfr[4];
    #pragma unroll
    for (int p = 0; p < 4; ++p) {
      const int ks = p >> 1, half = p & 1;
      bf16x8 afr[4];
      #pragma unroll
      for (int q = 0; q < 4; ++q) {
        int row = wm * 128 + half * 64 + q * 16 + l15;
        int unit = (ks * 4 + g) ^ (row & 7);
        afr[q] = *(const bf16x8*)(sac + row * 128 + unit * 16);
      }
      if (half == 0) {
        #pragma unroll
        for (int q = 0; q < 4; ++q) {
          int row = wn * 64 + q * 16 + l15;
          int unit = (ks * 4 + g) ^ (row & 7);
          bfr[q] = *(const bf16x8*)(sbc + row * 128 + unit * 16);
        }
      }
      if (tt < 7 && p < 2) {   // issue next-tile staging, phases 0-1 only
        #pragma unroll
        for (int i = p * 2; i < p * 2 + 2; ++i) {
          int chunk = i * 512 + t;
          int row = chunk >> 3, unit = chunk & 7;
          int so = row * 1024 + (tt + 1) * 128 + ((unit ^ (row & 7)) << 4);
          gload_lds16(Abase + so, san + i * 8192 + wave * 1024);
          gload_lds16(Bbase + so, sbn + i * 8192 + wave * 1024);
        }
      }
      asm volatile("s_barrier" ::: "memory");
      __builtin_amdgcn_s_setprio(1);
      #pragma unroll
      for (int q = 0; q < 4; ++q)
        #pragma unroll
        for (int ni = 0; ni < 4; ++ni)
          acc[half * 4 + q][ni] = mfma16(afr[q], bfr[ni], acc[half * 4 + q][ni]);
      __builtin_amdgcn_s_setprio(0);
      if (p == 3) {
        // next-tile loads (issued >=2 phases ago) must land before next iter
        asm volatile("s_waitcnt vmcnt(0)" ::: "memory");
      }
      asm volatile("s_barrier" ::: "memory");
    }
  }

  // epilogue: q pre-scaled by 0.125*log2(e)
  const float QSC = 0.1803368801f;
  #pragma unroll
  for (int ni = 0; ni < 4; ++ni) {
    int col = bn * 256 + wn * 64 + ni * 16 + l15;
    bf16* dst = qbuf + col;
    #pragma unroll
    for (int mi = 0; mi < 8; ++mi)
      #pragma unroll
      for (int jj = 0; jj < 4; ++jj) {
        size_t row = (size_t)bm * 256 + wm * 128 + mi * 16 + g * 4 + jj;
        dst[row * DIM] = (bf16)(acc[mi][ni][jj] * QSC);
      }
  }
}

// ---------------- k_gemm_kv: m97 128x128 on the 128 kv cols ---------------
__global__ __launch_bounds__(256) void k_gemm_kv(
    const bf16* __restrict__ xn, const bf16* __restrict__ wkv,
    bf16* __restrict__ kbuf, bf16* __restrict__ vtbuf) {
  __shared__ bf16 sa[2][128 * 32];
  __shared__ bf16 sb[2][128 * 32];
  const int t = threadIdx.x, wave = t >> 6, lane = t & 63;
  const int l15 = lane & 15, g = lane >> 4;
  const int wm = wave >> 1, wn = wave & 1;
  int wg = (blockIdx.x & 7) * 64 + (blockIdx.x >> 3);   // nwg=512=8*64
  const int bm = wg;
  const char* Abase = (const char*)(xn + (size_t)bm * 128 * DIM);
  const char* Bbase = (const char*)wkv;                 // 128 n-rows
  const int srow0 = wave * 16 + (lane >> 2);
  const int skb   = (lane & 3) * 16;

  #pragma unroll
  for (int c = 0; c < 2; ++c) {
    int row = c * 64 + srow0;
    int kb = skb ^ ((row & 3) << 4);
    gload_lds16(Abase + (size_t)row * 1024 + kb, (char*)&sa[0][0] + c * 4096 + wave * 1024);
    gload_lds16(Bbase + (size_t)row * 1024 + kb, (char*)&sb[0][0] + c * 4096 + wave * 1024);
  }
  __syncthreads();

  f32x4 acc[4][4];
  #pragma unroll
  for (int mi = 0; mi < 4; ++mi)
    #pragma unroll
    for (int ni = 0; ni < 4; ++ni) acc[mi][ni] = fzero4();

  #pragma unroll 2
  for (int step = 0; step < 16; ++step) {
    const int cur = step & 1;
    if (step < 15) {
      int kk2 = (step + 1) * 64;
      #pragma unroll
      for (int c = 0; c < 2; ++c) {
        int row = c * 64 + srow0;
        int kb = skb ^ ((row & 3) << 4);
        gload_lds16(Abase + (size_t)row * 1024 + kk2 + kb,
                    (char*)&sa[cur ^ 1][0] + c * 4096 + wave * 1024);
        gload_lds16(Bbase + (size_t)row * 1024 + kk2 + kb,
                    (char*)&sb[cur ^ 1][0] + c * 4096 + wave * 1024);
      }
    }
    bf16x8 a[4], b[4];
    #pragma unroll
    for (int mi = 0; mi < 4; ++mi) {
      int row = wm * 64 + mi * 16 + l15;
      a[mi] = *(const bf16x8*)((const char*)&sa[cur][0] + row * 64 + ((g * 16) ^ ((row & 3) << 4)));
    }
    #pragma unroll
    for (int ni = 0; ni < 4; ++ni) {
      int row = wn * 64 + ni * 16 + l15;
      b[ni] = *(const bf16x8*)((const char*)&sb[cur][0] + row * 64 + ((g * 16) ^ ((row & 3) << 4)));
    }
    #pragma unroll
    for (int mi = 0; mi < 4; ++mi)
      #pragma unroll
      for (int ni = 0; ni < 4; ++ni)
        acc[mi][ni] = mfma16(a[mi], b[ni], acc[mi][ni]);
    __syncthreads();
  }

  // epilogue: cols 0..63 -> k, 64..127 -> vT (b64 packed along jj)
  #pragma unroll
  for (int ni = 0; ni < 4; ++ni) {
    int col0 = wn * 64 + ni * 16;
    if (col0 < 64) {
      bf16* dst = kbuf + col0 + l15;
      #pragma unroll
      for (int mi = 0; mi < 4; ++mi)
        #pragma unroll
        for (int jj = 0; jj < 4; ++jj) {
          size_t row = (size_t)bm * 128 + wm * 64 + mi * 16 + g * 4 + jj;
          dst[row * DHEAD] = (bf16)acc[mi][ni][jj];
        }
    } else {
      int d = col0 - 64 + l15;
      #pragma unroll
      for (int mi = 0; mi < 4; ++mi) {
        size_t row = (size_t)bm * 128 + wm * 64 + mi * 16 + g * 4;
        int bnr = (int)(row >> 8), kv = (int)(row & 255);
        bf16x4 v4;
        v4[0] = (bf16)acc[mi][ni][0]; v4[1] = (bf16)acc[mi][ni][1];
        v4[2] = (bf16)acc[mi][ni][2]; v4[3] = (bf16)acc[mi][ni][3];
        *(bf16x4*)(vtbuf + (size_t)bnr * 16384 + (size_t)d * 256 + kv) = v4;
      }
    }
  }
}

// ---------------- k_out_fused: out-proj GEMM (BM=64 x BN=512) + LN -> f32 ---
__global__ __launch_bounds__(512) void k_out_fused(
    const bf16* __restrict__ abuf, const bf16* __restrict__ woutt,
    const float* __restrict__ gout, float* __restrict__ out) {
  __shared__ bf16 sa[2][64 * 32];     // 2 x 4 KB
  __shared__ bf16 sb[2][512 * 32];    // 2 x 32 KB
  __shared__ float2 part[64][4];
  __shared__ float2 stats[64];
  const int t = threadIdx.x, wave = t >> 6, lane = t & 63;
  const int l15 = lane & 15, g = lane >> 4;
  const int wm = wave >> 2, wn = wave & 3;
  int wg = (blockIdx.x & 7) * 128 + (blockIdx.x >> 3);   // nwg=1024=8*128
  const size_t row0 = (size_t)wg * 64;
  const char* Abase = (const char*)(abuf + row0 * DIM);
  const int nsub = wave * 16 + (lane >> 2);
  const int skb  = (lane & 3) * 16;

  #pragma unroll
  for (int c = 0; c < 4; ++c) {
    int row = c * 128 + nsub;
    int kb = skb ^ ((row & 3) << 4);
    gload_lds16((const char*)(woutt + (size_t)row * DIM) + kb,
                (char*)&sb[0][0] + c * 8192 + wave * 1024);
  }
  if (t < 256) {
    int kb = skb ^ ((nsub & 3) << 4);
    gload_lds16(Abase + (size_t)nsub * 1024 + kb,
                (char*)&sa[0][0] + wave * 1024 + (lane & 63) * 16);
  }
  __syncthreads();

  f32x4 acc[2][8];
  #pragma unroll
  for (int mi = 0; mi < 2; ++mi)
    #pragma unroll
    for (int ni = 0; ni < 8; ++ni) acc[mi][ni] = fzero4();

  #pragma unroll 2
  for (int step = 0; step < 16; ++step) {
    const int cur = step & 1;
    if (step < 15) {
      int kk2 = (step + 1) * 64;
      #pragma unroll
      for (int c = 0; c < 4; ++c) {
        int row = c * 128 + nsub;
        int kb = skb ^ ((row & 3) << 4);
        gload_lds16((const char*)(woutt + (size_t)row * DIM) + kk2 + kb,
                    (char*)&sb[cur ^ 1][0] + c * 8192 + wave * 1024);
      }
      if (t < 256) {
        int kb = skb ^ ((nsub & 3) << 4);
        gload_lds16(Abase + (size_t)nsub * 1024 + kk2 + kb,
                    (char*)&sa[cur ^ 1][0] + wave * 1024 + lane * 16);
      }
    }
    bf16x8 a[2];
    #pragma unroll
    for (int mi = 0; mi < 2; ++mi) {
      int row = wm * 32 + mi * 16 + l15;
      a[mi] = *(const bf16x8*)((const char*)&sa[cur][0] + row * 64 + ((g * 16) ^ ((row & 3) << 4)));
    }
    #pragma unroll
    for (int ni = 0; ni < 8; ++ni) {
      int row = wn * 128 + ni * 16 + l15;
      bf16x8 b = *(const bf16x8*)((const char*)&sb[cur][0] + row * 64 + ((g * 16) ^ ((row & 3) << 4)));
      acc[0][ni] = mfma16(a[0], b, acc[0][ni]);
      acc[1][ni] = mfma16(a[1], b, acc[1][ni]);
    }
    __syncthreads();
  }

  #pragma unroll
  for (int mi = 0; mi < 2; ++mi)
    #pragma unroll
    for (int jj = 0; jj < 4; ++jj) {
      float s = 0.f, q = 0.f;
      #pragma unroll
      for (int ni = 0; ni < 8; ++ni) {
        float v = acc[mi][ni][jj];
        s += v; q += v * v;
      }
      s += __shfl_xor(s, 1); q += __shfl_xor(q, 1);
      s += __shfl_xor(s, 2); q += __shfl_xor(q, 2);
      s += __shfl_xor(s, 4); q += __shfl_xor(q, 4);
      s += __shfl_xor(s, 8); q += __shfl_xor(q, 8);
      if (l15 == 0) part[wm * 32 + mi * 16 + g * 4 + jj][wn] = make_float2(s, q);
    }
  __syncthreads();
  if (t < 64) {
    float S = 0.f, Q = 0.f;
    #pragma unroll
    for (int w = 0; w < 4; ++w) { S += part[t][w].x; Q += part[t][w].y; }
    float mean = S * (1.f / 512.f);
    float var  = Q * (1.f / 512.f) - mean * mean;
    stats[t] = make_float2(mean, rsqrtf(var + 1e-5f));
  }
  __syncthreads();

  #pragma unroll
  for (int mi = 0; mi < 2; ++mi)
    #pragma unroll
    for (int ni = 0; ni < 8; ++ni) {
      int col = wn * 128 + ni * 16 + l15;
      float gg = gout[col];
      #pragma unroll
      for (int jj = 0; jj < 4; ++jj) {
        int row = wm * 32 + mi * 16 + g * 4 + jj;
        float2 st = stats[row];
        out[(row0 + row) * DIM + col] = (acc[mi][ni][jj] - st.x) * st.y * gg;
      }
    }
}

// ---------------- k_attn: no-max fused softmax pipeline --------------------
// q arrives PRE-SCALED by 0.125*log2(e) -> p = exp2f(s) directly.
__global__ __launch_bounds__(512, 2) void k_attn(
    bf16* __restrict__ qbuf, const bf16* __restrict__ kbuf,
    const bf16* __restrict__ vtbuf) {
  __shared__ char lds[256 * 144 + 64 * 528];   // lk | lvt, 69 KB
  char* lk  = lds;                  // [kv row][72 bf16] (64 data + 8 pad)
  char* lvt = lds + 256 * 144;      // [d row][264 bf16] (256 data + 8 pad)
  const int t = threadIdx.x, lane = t & 63;
  const int l15 = lane & 15, g = lane >> 4;
  int wg = (blockIdx.x & 7) * 256 + (blockIdx.x >> 3);  // 8 heads/bn per XCD
  const int bn = wg >> 3, h = wg & 7;
  const size_t tok0 = (size_t)bn * RLEN;
  const int m0 = (t >> 6) * 32;

  bf16x8 aq[2][2];
  {
    const bf16* qb = qbuf + (tok0 + m0 + l15) * DIM + h * DHEAD + g * 8;
    #pragma unroll
    for (int qh = 0; qh < 2; ++qh)
      #pragma unroll
      for (int ks = 0; ks < 2; ++ks)
        aq[qh][ks] = *(const bf16x8*)(qb + (size_t)qh * 16 * DIM + ks * 32);
  }
  {
    const bf16* ksrc = kbuf + tok0 * DHEAD;
    const bf16* vsrc = vtbuf + (size_t)bn * (64 * 256);
    bf16x8 kr[4], vr[4];
    #pragma unroll
    for (int i = 0; i < 4; ++i) kr[i] = *(const bf16x8*)(ksrc + (i * 512 + t) * 8);
    #pragma unroll
    for (int i = 0; i < 4; ++i) vr[i] = *(const bf16x8*)(vsrc + (i * 512 + t) * 8);
    #pragma unroll
    for (int i = 0; i < 4; ++i) {
      int off = i * 512 + t;
      *(bf16x8*)(lk + (off >> 3) * 144 + (off & 7) * 16) = kr[i];
    }
    #pragma unroll
    for (int i = 0; i < 4; ++i) {
      int off = i * 512 + t;
      *(bf16x8*)(lvt + (off >> 5) * 528 + (off & 31) * 16) = vr[i];
    }
  }
  __syncthreads();   // single barrier

  const char* bk_base = lk  + l15 * 144 + g * 16;
  const char* bv_base = lvt + l15 * 528 + g * 8;

  f32x4 o2[2][4];
  #pragma unroll
  for (int qh = 0; qh < 2; ++qh)
    #pragma unroll
    for (int di = 0; di < 4; ++di) o2[qh][di] = fzero4();
  float lsum0 = 0.f, lsum1 = 0.f;

  __builtin_amdgcn_s_setprio(1);
  #pragma unroll
  for (int f = 0; f < 16; ++f) {
    bf16x8 bk0 = *(const bf16x8*)(bk_base + f * 2304);
    bf16x8 bk1 = *(const bf16x8*)(bk_base + f * 2304 + 64);
    f32x4 s0 = mfma16(bk0, aq[0][0], fzero4());
    s0 = mfma16(bk1, aq[0][1], s0);
    f32x4 s1 = mfma16(bk0, aq[1][0], fzero4());
    s1 = mfma16(bk1, aq[1][1], s1);
    float p00 = exp2f(s0[0]), p01 = exp2f(s0[1]);
    float p02 = exp2f(s0[2]), p03 = exp2f(s0[3]);
    float p10 = exp2f(s1[0]), p11 = exp2f(s1[1]);
    float p12 = exp2f(s1[2]), p13 = exp2f(s1[3]);
    lsum0 += (p00 + p01) + (p02 + p03);
    lsum1 += (p10 + p11) + (p12 + p13);
    bf16x4 pk0, pk1;
    pk0[0] = (bf16)p00; pk0[1] = (bf16)p01; pk0[2] = (bf16)p02; pk0[3] = (bf16)p03;
    pk1[0] = (bf16)p10; pk1[1] = (bf16)p11; pk1[2] = (bf16)p12; pk1[3] = (bf16)p13;
    #pragma unroll
    for (int di = 0; di < 4; ++di) {
      bf16x4 bv = *(const bf16x4*)(bv_base + di * 8448 + f * 32);
      o2[0][di] = mfma_k16(pk0, bv, o2[0][di]);
      o2[1][di] = mfma_k16(pk1, bv, o2[1][di]);
    }
  }
  __builtin_amdgcn_s_setprio(0);

  float linv[2];
  lsum0 += __shfl_xor(lsum0, 16); lsum0 += __shfl_xor(lsum0, 32);
  lsum1 += __shfl_xor(lsum1, 16); lsum1 += __shfl_xor(lsum1, 32);
  linv[0] = 1.0f / lsum0;
  linv[1] = 1.0f / lsum1;

  #pragma unroll
  for (int qh = 0; qh < 2; ++qh)
    #pragma unroll
    for (int jj = 0; jj < 4; ++jj) {
      float inv = __shfl(linv[qh], 4 * g + jj);
      size_t row = tok0 + m0 + qh * 16 + 4 * g + jj;
      #pragma unroll
      for (int di = 0; di < 4; ++di)
        qbuf[row * DIM + h * DHEAD + di * 16 + l15] = (bf16)(o2[qh][di][jj] * inv);
    }
}

// ---------------- launch ----------------
extern "C" void kernel_launch(void* const* d_in, const int* in_sizes, int n_in,
                              void* d_out, int out_size, void* d_ws, size_t ws_size,
                              hipStream_t stream) {
  const float* x     = (const float*)d_in[0];
  const float* gnorm = (const float*)d_in[1];
  const float* Wq    = (const float*)d_in[2];
  const float* Wkv   = (const float*)d_in[3];
  const float* Wout  = (const float*)d_in[4];
  const float* gout  = (const float*)d_in[5];
  float* out = (float*)d_out;
  char* ws = (char*)d_ws;
  // ws: wall 640K | woutt 512K | xnbuf 64M | qbuf 64M | kbuf 8M | vtbuf 8M
  bf16* wall  = (bf16*)(ws);
  bf16* woutt = (bf16*)(ws + 655360);
  bf16* xnbuf = (bf16*)(ws + 1179648);
  bf16* qbuf  = (bf16*)(ws + 1179648 + (size_t)TOK * DIM * 2);
  bf16* kbuf  = (bf16*)((char*)qbuf + (size_t)TOK * DIM * 2);
  bf16* vtbuf = (bf16*)((char*)kbuf + (size_t)TOK * DHEAD * 2);

  k_prep     <<<dim3(1280), dim3(256), 0, stream>>>(Wq, Wkv, Wout, wall, woutt);
  kx_ln      <<<dim3(2048), dim3(256), 0, stream>>>(x, gnorm, xnbuf);
  k_gemm_q   <<<dim3(512),  dim3(512), 0, stream>>>(xnbuf, wall, qbuf);
  k_gemm_kv  <<<dim3(512),  dim3(256), 0, stream>>>(xnbuf, wall + (size_t)512 * DIM, kbuf, vtbuf);
  k_attn     <<<dim3(2048), dim3(512), 0, stream>>>(qbuf, kbuf, vtbuf);
  k_out_fused<<<dim3(1024), dim3(512), 0, stream>>>(qbuf, woutt, gout, out);
}

// Round 13
// 240.790 us; speedup vs baseline: 1.0522x; 1.0522x over previous
//
#include <hip/hip_runtime.h>
#include <stdint.h>

// Pipeline: k_prep_ln (weights->bf16 + LN(x)->bf16, one grid) |
// k_gemm_qkv (m97 128x128 -> q*QSC, k, vT) | k_attn (no-max pipeline) |
// k_out_fused (out-proj + LN).  x[4,64,256,512]; heads=8, dhead=64.

#define DIM   512
#define DHEAD 64
#define RLEN  256
#define TOK   65536

typedef __bf16 bf16;
typedef __bf16 bf16x4 __attribute__((ext_vector_type(4)));
typedef __bf16 bf16x8 __attribute__((ext_vector_type(8)));
typedef float  f32x4  __attribute__((ext_vector_type(4)));
typedef short  s16x4  __attribute__((ext_vector_type(4)));

__device__ __forceinline__ f32x4 mfma16(bf16x8 a, bf16x8 b, f32x4 c) {
  return __builtin_amdgcn_mfma_f32_16x16x32_bf16(a, b, c, 0, 0, 0);
}
__device__ __forceinline__ f32x4 mfma_k16(bf16x4 a, bf16x4 b, f32x4 c) {
#if __has_builtin(__builtin_amdgcn_mfma_f32_16x16x16bf16_1k)
  return __builtin_amdgcn_mfma_f32_16x16x16bf16_1k(
      __builtin_bit_cast(s16x4, a), __builtin_bit_cast(s16x4, b), c, 0, 0, 0);
#else
  f32x4 d = c;
  asm volatile("v_mfma_f32_16x16x16_bf16 %0, %1, %2, %0"
               : "+v"(d) : "v"(a), "v"(b));
  return d;
#endif
}
__device__ __forceinline__ f32x4 fzero4() {
  f32x4 z; z[0] = z[1] = z[2] = z[3] = 0.f; return z;
}
__device__ __forceinline__ void gload_lds16(const void* g, void* l) {
  __builtin_amdgcn_global_load_lds(
      (const __attribute__((address_space(1))) void*)g,
      (__attribute__((address_space(3))) void*)l, 16, 0, 0);
}

// ---------------- k_prep_ln: weight prep (blocks<1280) + LN(x) (rest) ------
__global__ __launch_bounds__(256) void k_prep_ln(
    const float* __restrict__ Wq, const float* __restrict__ Wkv,
    const float* __restrict__ Wout,
    const float* __restrict__ x, const float* __restrict__ gnorm,
    bf16* __restrict__ wall, bf16* __restrict__ woutt, bf16* __restrict__ xn) {
  if (blockIdx.x < 1280) {
    int t = blockIdx.x * 256 + threadIdx.x;   // covers 640*512
    int n = t >> 9, k = t & 511;
    float v = (n < DIM) ? Wq[k * DIM + n] : Wkv[k * 128 + (n - DIM)];
    wall[t] = (bf16)v;
    if (t < DIM * DIM) woutt[t] = (bf16)Wout[k * DIM + n];
    return;
  }
  const int lane = threadIdx.x & 63;
  const int gw = (blockIdx.x - 1280) * 4 + (threadIdx.x >> 6);
  float gv[8];
  #pragma unroll
  for (int j = 0; j < 8; ++j) gv[j] = gnorm[lane * 8 + j];
  #pragma unroll
  for (int i = 0; i < 8; ++i) {
    size_t row = (size_t)gw * 8 + i;
    const float4* xp = (const float4*)(x + row * DIM + lane * 8);
    float4 v0 = xp[0], v1 = xp[1];
    float s  = v0.x + v0.y + v0.z + v0.w + v1.x + v1.y + v1.z + v1.w;
    float sq = v0.x*v0.x + v0.y*v0.y + v0.z*v0.z + v0.w*v0.w
             + v1.x*v1.x + v1.y*v1.y + v1.z*v1.z + v1.w*v1.w;
    #pragma unroll
    for (int d = 1; d < 64; d <<= 1) { s += __shfl_xor(s, d); sq += __shfl_xor(sq, d); }
    float mean = s * (1.f / 512.f);
    float var  = sq * (1.f / 512.f) - mean * mean;
    float rs   = rsqrtf(var + 1e-5f);
    bf16x8 o;
    o[0] = (bf16)((v0.x - mean) * rs * gv[0]);
    o[1] = (bf16)((v0.y - mean) * rs * gv[1]);
    o[2] = (bf16)((v0.z - mean) * rs * gv[2]);
    o[3] = (bf16)((v0.w - mean) * rs * gv[3]);
    o[4] = (bf16)((v1.x - mean) * rs * gv[4]);
    o[5] = (bf16)((v1.y - mean) * rs * gv[5]);
    o[6] = (bf16)((v1.z - mean) * rs * gv[6]);
    o[7] = (bf16)((v1.w - mean) * rs * gv[7]);
    *(bf16x8*)(xn + row * DIM + lane * 8) = o;
  }
}

// ---------------- k_gemm_qkv: m97 128x128, [M,640] = xn @ wall^T -----------
// q columns pre-scaled by 0.125*log2(e) so attn uses exp2f(s) directly.
__global__ __launch_bounds__(256) void k_gemm_qkv(
    const bf16* __restrict__ xn, const bf16* __restrict__ wall,
    bf16* __restrict__ qbuf, bf16* __restrict__ kbuf, bf16* __restrict__ vtbuf) {
  __shared__ bf16 sa[2][128 * 32];
  __shared__ bf16 sb[2][128 * 32];
  const int t = threadIdx.x, wave = t >> 6, lane = t & 63;
  const int l15 = lane & 15, g = lane >> 4;
  const int wm = wave >> 1, wn = wave & 1;
  int wg = (blockIdx.x & 7) * 320 + (blockIdx.x >> 3);   // nwg=2560=8*320
  const int bm = wg / 5, bn = wg % 5;
  const char* Abase = (const char*)(xn   + (size_t)bm * 128 * DIM);
  const char* Bbase = (const char*)(wall + (size_t)bn * 128 * DIM);
  const int srow0 = wave * 16 + (lane >> 2);
  const int skb   = (lane & 3) * 16;

  #pragma unroll
  for (int c = 0; c < 2; ++c) {
    int row = c * 64 + srow0;
    int kb = skb ^ ((row & 3) << 4);
    gload_lds16(Abase + (size_t)row * 1024 + kb, (char*)&sa[0][0] + c * 4096 + wave * 1024);
    gload_lds16(Bbase + (size_t)row * 1024 + kb, (char*)&sb[0][0] + c * 4096 + wave * 1024);
  }
  __syncthreads();

  f32x4 acc[4][4];
  #pragma unroll
  for (int mi = 0; mi < 4; ++mi)
    #pragma unroll
    for (int ni = 0; ni < 4; ++ni) acc[mi][ni] = fzero4();

  #pragma unroll 2
  for (int step = 0; step < 16; ++step) {
    const int cur = step & 1;
    if (step < 15) {
      int kk2 = (step + 1) * 64;
      #pragma unroll
      for (int c = 0; c < 2; ++c) {
        int row = c * 64 + srow0;
        int kb = skb ^ ((row & 3) << 4);
        gload_lds16(Abase + (size_t)row * 1024 + kk2 + kb,
                    (char*)&sa[cur ^ 1][0] + c * 4096 + wave * 1024);
        gload_lds16(Bbase + (size_t)row * 1024 + kk2 + kb,
                    (char*)&sb[cur ^ 1][0] + c * 4096 + wave * 1024);
      }
    }
    bf16x8 a[4], b[4];
    #pragma unroll
    for (int mi = 0; mi < 4; ++mi) {
      int row = wm * 64 + mi * 16 + l15;
      a[mi] = *(const bf16x8*)((const char*)&sa[cur][0] + row * 64 + ((g * 16) ^ ((row & 3) << 4)));
    }
    #pragma unroll
    for (int ni = 0; ni < 4; ++ni) {
      int row = wn * 64 + ni * 16 + l15;
      b[ni] = *(const bf16x8*)((const char*)&sb[cur][0] + row * 64 + ((g * 16) ^ ((row & 3) << 4)));
    }
    #pragma unroll
    for (int mi = 0; mi < 4; ++mi)
      #pragma unroll
      for (int ni = 0; ni < 4; ++ni)
        acc[mi][ni] = mfma16(a[mi], b[ni], acc[mi][ni]);
    __syncthreads();
  }

  // epilogue: route cols to q (pre-scaled) / k / vT
  const float QSC = 0.1803368801f;   // 0.125 * log2(e)
  #pragma unroll
  for (int ni = 0; ni < 4; ++ni) {
    int col0 = bn * 128 + wn * 64 + ni * 16;
    if (col0 < 512) {
      bf16* dst = qbuf + col0 + l15;
      #pragma unroll
      for (int mi = 0; mi < 4; ++mi)
        #pragma unroll
        for (int jj = 0; jj < 4; ++jj) {
          size_t row = (size_t)bm * 128 + wm * 64 + mi * 16 + g * 4 + jj;
          dst[row * DIM] = (bf16)(acc[mi][ni][jj] * QSC);
        }
    } else if (col0 < 576) {
      bf16* dst = kbuf + (col0 - 512) + l15;
      #pragma unroll
      for (int mi = 0; mi < 4; ++mi)
        #pragma unroll
        for (int jj = 0; jj < 4; ++jj) {
          size_t row = (size_t)bm * 128 + wm * 64 + mi * 16 + g * 4 + jj;
          dst[row * DHEAD] = (bf16)acc[mi][ni][jj];
        }
    } else {
      // vT[bn_r][d][kv]: jj is kv-contiguous -> packed b64 store
      int d = col0 - 576 + l15;
      #pragma unroll
      for (int mi = 0; mi < 4; ++mi) {
        size_t row = (size_t)bm * 128 + wm * 64 + mi * 16 + g * 4;
        int bnr = (int)(row >> 8), kv = (int)(row & 255);
        bf16x4 v4;
        v4[0] = (bf16)acc[mi][ni][0]; v4[1] = (bf16)acc[mi][ni][1];
        v4[2] = (bf16)acc[mi][ni][2]; v4[3] = (bf16)acc[mi][ni][3];
        *(bf16x4*)(vtbuf + (size_t)bnr * 16384 + (size_t)d * 256 + kv) = v4;
      }
    }
  }
}

// ---------------- k_out_fused: out-proj GEMM (BM=64 x BN=512) + LN -> f32 ---
__global__ __launch_bounds__(512) void k_out_fused(
    const bf16* __restrict__ abuf, const bf16* __restrict__ woutt,
    const float* __restrict__ gout, float* __restrict__ out) {
  __shared__ bf16 sa[2][64 * 32];     // 2 x 4 KB
  __shared__ bf16 sb[2][512 * 32];    // 2 x 32 KB
  __shared__ float2 part[64][4];
  __shared__ float2 stats[64];
  const int t = threadIdx.x, wave = t >> 6, lane = t & 63;
  const int l15 = lane & 15, g = lane >> 4;
  const int wm = wave >> 2, wn = wave & 3;
  int wg = (blockIdx.x & 7) * 128 + (blockIdx.x >> 3);   // nwg=1024=8*128
  const size_t row0 = (size_t)wg * 64;
  const char* Abase = (const char*)(abuf + row0 * DIM);
  const int nsub = wave * 16 + (lane >> 2);
  const int skb  = (lane & 3) * 16;

  #pragma unroll
  for (int c = 0; c < 4; ++c) {
    int row = c * 128 + nsub;
    int kb = skb ^ ((row & 3) << 4);
    gload_lds16((const char*)(woutt + (size_t)row * DIM) + kb,
                (char*)&sb[0][0] + c * 8192 + wave * 1024);
  }
  if (t < 256) {
    int kb = skb ^ ((nsub & 3) << 4);
    gload_lds16(Abase + (size_t)nsub * 1024 + kb,
                (char*)&sa[0][0] + wave * 1024 + (lane & 63) * 16);
  }
  __syncthreads();

  f32x4 acc[2][8];
  #pragma unroll
  for (int mi = 0; mi < 2; ++mi)
    #pragma unroll
    for (int ni = 0; ni < 8; ++ni) acc[mi][ni] = fzero4();

  #pragma unroll 2
  for (int step = 0; step < 16; ++step) {
    const int cur = step & 1;
    if (step < 15) {
      int kk2 = (step + 1) * 64;
      #pragma unroll
      for (int c = 0; c < 4; ++c) {
        int row = c * 128 + nsub;
        int kb = skb ^ ((row & 3) << 4);
        gload_lds16((const char*)(woutt + (size_t)row * DIM) + kk2 + kb,
                    (char*)&sb[cur ^ 1][0] + c * 8192 + wave * 1024);
      }
      if (t < 256) {
        int kb = skb ^ ((nsub & 3) << 4);
        gload_lds16(Abase + (size_t)nsub * 1024 + kk2 + kb,
                    (char*)&sa[cur ^ 1][0] + wave * 1024 + lane * 16);
      }
    }
    bf16x8 a[2];
    #pragma unroll
    for (int mi = 0; mi < 2; ++mi) {
      int row = wm * 32 + mi * 16 + l15;
      a[mi] = *(const bf16x8*)((const char*)&sa[cur][0] + row * 64 + ((g * 16) ^ ((row & 3) << 4)));
    }
    #pragma unroll
    for (int ni = 0; ni < 8; ++ni) {
      int row = wn * 128 + ni * 16 + l15;
      bf16x8 b = *(const bf16x8*)((const char*)&sb[cur][0] + row * 64 + ((g * 16) ^ ((row & 3) << 4)));
      acc[0][ni] = mfma16(a[0], b, acc[0][ni]);
      acc[1][ni] = mfma16(a[1], b, acc[1][ni]);
    }
    __syncthreads();
  }

  #pragma unroll
  for (int mi = 0; mi < 2; ++mi)
    #pragma unroll
    for (int jj = 0; jj < 4; ++jj) {
      float s = 0.f, q = 0.f;
      #pragma unroll
      for (int ni = 0; ni < 8; ++ni) {
        float v = acc[mi][ni][jj];
        s += v; q += v * v;
      }
      s += __shfl_xor(s, 1); q += __shfl_xor(q, 1);
      s += __shfl_xor(s, 2); q += __shfl_xor(q, 2);
      s += __shfl_xor(s, 4); q += __shfl_xor(q, 4);
      s += __shfl_xor(s, 8); q += __shfl_xor(q, 8);
      if (l15 == 0) part[wm * 32 + mi * 16 + g * 4 + jj][wn] = make_float2(s, q);
    }
  __syncthreads();
  if (t < 64) {
    float S = 0.f, Q = 0.f;
    #pragma unroll
    for (int w = 0; w < 4; ++w) { S += part[t][w].x; Q += part[t][w].y; }
    float mean = S * (1.f / 512.f);
    float var  = Q * (1.f / 512.f) - mean * mean;
    stats[t] = make_float2(mean, rsqrtf(var + 1e-5f));
  }
  __syncthreads();

  #pragma unroll
  for (int mi = 0; mi < 2; ++mi)
    #pragma unroll
    for (int ni = 0; ni < 8; ++ni) {
      int col = wn * 128 + ni * 16 + l15;
      float gg = gout[col];
      #pragma unroll
      for (int jj = 0; jj < 4; ++jj) {
        int row = wm * 32 + mi * 16 + g * 4 + jj;
        float2 st = stats[row];
        out[(row0 + row) * DIM + col] = (acc[mi][ni][jj] - st.x) * st.y * gg;
      }
    }
}

// ---------------- k_attn: no-max fused softmax pipeline --------------------
// q arrives PRE-SCALED by 0.125*log2(e) -> p = exp2f(s) directly.
__global__ __launch_bounds__(512, 2) void k_attn(
    bf16* __restrict__ qbuf, const bf16* __restrict__ kbuf,
    const bf16* __restrict__ vtbuf) {
  __shared__ char lds[256 * 144 + 64 * 528];   // lk | lvt, 69 KB
  char* lk  = lds;                  // [kv row][72 bf16] (64 data + 8 pad)
  char* lvt = lds + 256 * 144;      // [d row][264 bf16] (256 data + 8 pad)
  const int t = threadIdx.x, lane = t & 63;
  const int l15 = lane & 15, g = lane >> 4;
  int wg = (blockIdx.x & 7) * 256 + (blockIdx.x >> 3);  // 8 heads/bn per XCD
  const int bn = wg >> 3, h = wg & 7;
  const size_t tok0 = (size_t)bn * RLEN;
  const int m0 = (t >> 6) * 32;

  bf16x8 aq[2][2];
  {
    const bf16* qb = qbuf + (tok0 + m0 + l15) * DIM + h * DHEAD + g * 8;
    #pragma unroll
    for (int qh = 0; qh < 2; ++qh)
      #pragma unroll
      for (int ks = 0; ks < 2; ++ks)
        aq[qh][ks] = *(const bf16x8*)(qb + (size_t)qh * 16 * DIM + ks * 32);
  }
  {
    const bf16* ksrc = kbuf + tok0 * DHEAD;
    const bf16* vsrc = vtbuf + (size_t)bn * (64 * 256);
    bf16x8 kr[4], vr[4];
    #pragma unroll
    for (int i = 0; i < 4; ++i) kr[i] = *(const bf16x8*)(ksrc + (i * 512 + t) * 8);
    #pragma unroll
    for (int i = 0; i < 4; ++i) vr[i] = *(const bf16x8*)(vsrc + (i * 512 + t) * 8);
    #pragma unroll
    for (int i = 0; i < 4; ++i) {
      int off = i * 512 + t;
      *(bf16x8*)(lk + (off >> 3) * 144 + (off & 7) * 16) = kr[i];
    }
    #pragma unroll
    for (int i = 0; i < 4; ++i) {
      int off = i * 512 + t;
      *(bf16x8*)(lvt + (off >> 5) * 528 + (off & 31) * 16) = vr[i];
    }
  }
  __syncthreads();   // single barrier

  const char* bk_base = lk  + l15 * 144 + g * 16;
  const char* bv_base = lvt + l15 * 528 + g * 8;

  f32x4 o2[2][4];
  #pragma unroll
  for (int qh = 0; qh < 2; ++qh)
    #pragma unroll
    for (int di = 0; di < 4; ++di) o2[qh][di] = fzero4();
  float lsum0 = 0.f, lsum1 = 0.f;

  __builtin_amdgcn_s_setprio(1);
  #pragma unroll
  for (int f = 0; f < 16; ++f) {
    bf16x8 bk0 = *(const bf16x8*)(bk_base + f * 2304);
    bf16x8 bk1 = *(const bf16x8*)(bk_base + f * 2304 + 64);
    f32x4 s0 = mfma16(bk0, aq[0][0], fzero4());
    s0 = mfma16(bk1, aq[0][1], s0);
    f32x4 s1 = mfma16(bk0, aq[1][0], fzero4());
    s1 = mfma16(bk1, aq[1][1], s1);
    float p00 = exp2f(s0[0]), p01 = exp2f(s0[1]);
    float p02 = exp2f(s0[2]), p03 = exp2f(s0[3]);
    float p10 = exp2f(s1[0]), p11 = exp2f(s1[1]);
    float p12 = exp2f(s1[2]), p13 = exp2f(s1[3]);
    lsum0 += (p00 + p01) + (p02 + p03);
    lsum1 += (p10 + p11) + (p12 + p13);
    bf16x4 pk0, pk1;
    pk0[0] = (bf16)p00; pk0[1] = (bf16)p01; pk0[2] = (bf16)p02; pk0[3] = (bf16)p03;
    pk1[0] = (bf16)p10; pk1[1] = (bf16)p11; pk1[2] = (bf16)p12; pk1[3] = (bf16)p13;
    #pragma unroll
    for (int di = 0; di < 4; ++di) {
      bf16x4 bv = *(const bf16x4*)(bv_base + di * 8448 + f * 32);
      o2[0][di] = mfma_k16(pk0, bv, o2[0][di]);
      o2[1][di] = mfma_k16(pk1, bv, o2[1][di]);
    }
  }
  __builtin_amdgcn_s_setprio(0);

  float linv[2];
  lsum0 += __shfl_xor(lsum0, 16); lsum0 += __shfl_xor(lsum0, 32);
  lsum1 += __shfl_xor(lsum1, 16); lsum1 += __shfl_xor(lsum1, 32);
  linv[0] = 1.0f / lsum0;
  linv[1] = 1.0f / lsum1;

  #pragma unroll
  for (int qh = 0; qh < 2; ++qh)
    #pragma unroll
    for (int jj = 0; jj < 4; ++jj) {
      float inv = __shfl(linv[qh], 4 * g + jj);
      size_t row = tok0 + m0 + qh * 16 + 4 * g + jj;
      #pragma unroll
      for (int di = 0; di < 4; ++di)
        qbuf[row * DIM + h * DHEAD + di * 16 + l15] = (bf16)(o2[qh][di][jj] * inv);
    }
}

// ---------------- launch ----------------
extern "C" void kernel_launch(void* const* d_in, const int* in_sizes, int n_in,
                              void* d_out, int out_size, void* d_ws, size_t ws_size,
                              hipStream_t stream) {
  const float* x     = (const float*)d_in[0];
  const float* gnorm = (const float*)d_in[1];
  const float* Wq    = (const float*)d_in[2];
  const float* Wkv   = (const float*)d_in[3];
  const float* Wout  = (const float*)d_in[4];
  const float* gout  = (const float*)d_in[5];
  float* out = (float*)d_out;
  char* ws = (char*)d_ws;
  // ws: wall 640K | woutt 512K | xnbuf 64M | qbuf 64M | kbuf 8M | vtbuf 8M
  bf16* wall  = (bf16*)(ws);
  bf16* woutt = (bf16*)(ws + 655360);
  bf16* xnbuf = (bf16*)(ws + 1179648);
  bf16* qbuf  = (bf16*)(ws + 1179648 + (size_t)TOK * DIM * 2);
  bf16* kbuf  = (bf16*)((char*)qbuf + (size_t)TOK * DIM * 2);
  bf16* vtbuf = (bf16*)((char*)kbuf + (size_t)TOK * DHEAD * 2);

  k_prep_ln  <<<dim3(3328), dim3(256), 0, stream>>>(Wq, Wkv, Wout, x, gnorm,
                                                    wall, woutt, xnbuf);
  k_gemm_qkv <<<dim3(2560), dim3(256), 0, stream>>>(xnbuf, wall, qbuf, kbuf, vtbuf);
  k_attn     <<<dim3(2048), dim3(512), 0, stream>>>(qbuf, kbuf, vtbuf);
  k_out_fused<<<dim3(1024), dim3(512), 0, stream>>>(qbuf, woutt, gout, out);
}

// Round 14
// 236.557 us; speedup vs baseline: 1.0711x; 1.0179x over previous
//
#include <hip/hip_runtime.h>
#include <stdint.h>

// Pipeline: k_prep_ln (LDS-transpose weight prep, blocks 0..143 | LN(x), rest)
// | k_gemm_qkv (m97 128x128 -> q*QSC, k, vT) | k_attn (no-max pipeline) |
// k_out_fused (out-proj + LN).  x[4,64,256,512]; heads=8, dhead=64.

#define DIM   512
#define DHEAD 64
#define RLEN  256
#define TOK   65536

typedef __bf16 bf16;
typedef __bf16 bf16x4 __attribute__((ext_vector_type(4)));
typedef __bf16 bf16x8 __attribute__((ext_vector_type(8)));
typedef float  f32x4  __attribute__((ext_vector_type(4)));
typedef short  s16x4  __attribute__((ext_vector_type(4)));

__device__ __forceinline__ f32x4 mfma16(bf16x8 a, bf16x8 b, f32x4 c) {
  return __builtin_amdgcn_mfma_f32_16x16x32_bf16(a, b, c, 0, 0, 0);
}
__device__ __forceinline__ f32x4 mfma_k16(bf16x4 a, bf16x4 b, f32x4 c) {
#if __has_builtin(__builtin_amdgcn_mfma_f32_16x16x16bf16_1k)
  return __builtin_amdgcn_mfma_f32_16x16x16bf16_1k(
      __builtin_bit_cast(s16x4, a), __builtin_bit_cast(s16x4, b), c, 0, 0, 0);
#else
  f32x4 d = c;
  asm volatile("v_mfma_f32_16x16x16_bf16 %0, %1, %2, %0"
               : "+v"(d) : "v"(a), "v"(b));
  return d;
#endif
}
__device__ __forceinline__ f32x4 fzero4() {
  f32x4 z; z[0] = z[1] = z[2] = z[3] = 0.f; return z;
}
__device__ __forceinline__ void gload_lds16(const void* g, void* l) {
  __builtin_amdgcn_global_load_lds(
      (const __attribute__((address_space(1))) void*)g,
      (__attribute__((address_space(3))) void*)l, 16, 0, 0);
}

// ---------------- k_prep_ln ------------------------------------------------
// blocks 0..143: transpose one 64x64 tile of a weight matrix via LDS
//   (coalesced f32 row reads -> bf16 LDS -> coalesced [n][k] row writes).
//   0..63: Wq -> wall rows 0..511 | 64..127: Wout -> woutt | 128..143:
//   Wkv (N=128) -> wall rows 512..639.
// blocks >=144: LayerNorm(x)*g -> bf16 xn (unchanged).
__global__ __launch_bounds__(256) void k_prep_ln(
    const float* __restrict__ Wq, const float* __restrict__ Wkv,
    const float* __restrict__ Wout,
    const float* __restrict__ x, const float* __restrict__ gnorm,
    bf16* __restrict__ wall, bf16* __restrict__ woutt, bf16* __restrict__ xn) {
  if (blockIdx.x < 144) {
    __shared__ bf16 tile[64][72];
    const int b = blockIdx.x, tid = threadIdx.x;
    const float* src; bf16* dst; int srcN, kt, nt;
    if (b < 64)       { src = Wq;   dst = wall;  srcN = 512; kt = b >> 3;        nt = b & 7; }
    else if (b < 128) { src = Wout; dst = woutt; srcN = 512; kt = (b - 64) >> 3; nt = (b - 64) & 7; }
    else              { src = Wkv;  dst = wall + (size_t)512 * DIM; srcN = 128;
                        kt = (b - 128) >> 1; nt = (b - 128) & 1; }
    const int k0 = kt * 64, n0 = nt * 64;
    // read: 64 rows x 16 float4 (coalesced), convert, store LDS
    #pragma unroll
    for (int i = 0; i < 4; ++i) {
      int idx = i * 256 + tid;
      int r = idx >> 4, c4 = (idx & 15) * 4;
      float4 v = *(const float4*)(src + (size_t)(k0 + r) * srcN + n0 + c4);
      tile[r][c4 + 0] = (bf16)v.x;
      tile[r][c4 + 1] = (bf16)v.y;
      tile[r][c4 + 2] = (bf16)v.z;
      tile[r][c4 + 3] = (bf16)v.w;
    }
    __syncthreads();
    // write transposed: dst[n][k], 8 lanes per n-row, contiguous 128B
    #pragma unroll
    for (int i = 0; i < 2; ++i) {
      int idx = i * 256 + tid;
      int n = idx >> 3, c = (idx & 7) * 8;
      bf16x8 o;
      #pragma unroll
      for (int j = 0; j < 8; ++j) o[j] = tile[c + j][n];
      *(bf16x8*)(dst + (size_t)(n0 + n) * DIM + k0 + c) = o;
    }
    return;
  }
  const int lane = threadIdx.x & 63;
  const int gw = (blockIdx.x - 144) * 4 + (threadIdx.x >> 6);
  float gv[8];
  #pragma unroll
  for (int j = 0; j < 8; ++j) gv[j] = gnorm[lane * 8 + j];
  #pragma unroll
  for (int i = 0; i < 8; ++i) {
    size_t row = (size_t)gw * 8 + i;
    const float4* xp = (const float4*)(x + row * DIM + lane * 8);
    float4 v0 = xp[0], v1 = xp[1];
    float s  = v0.x + v0.y + v0.z + v0.w + v1.x + v1.y + v1.z + v1.w;
    float sq = v0.x*v0.x + v0.y*v0.y + v0.z*v0.z + v0.w*v0.w
             + v1.x*v1.x + v1.y*v1.y + v1.z*v1.z + v1.w*v1.w;
    #pragma unroll
    for (int d = 1; d < 64; d <<= 1) { s += __shfl_xor(s, d); sq += __shfl_xor(sq, d); }
    float mean = s * (1.f / 512.f);
    float var  = sq * (1.f / 512.f) - mean * mean;
    float rs   = rsqrtf(var + 1e-5f);
    bf16x8 o;
    o[0] = (bf16)((v0.x - mean) * rs * gv[0]);
    o[1] = (bf16)((v0.y - mean) * rs * gv[1]);
    o[2] = (bf16)((v0.z - mean) * rs * gv[2]);
    o[3] = (bf16)((v0.w - mean) * rs * gv[3]);
    o[4] = (bf16)((v1.x - mean) * rs * gv[4]);
    o[5] = (bf16)((v1.y - mean) * rs * gv[5]);
    o[6] = (bf16)((v1.z - mean) * rs * gv[6]);
    o[7] = (bf16)((v1.w - mean) * rs * gv[7]);
    *(bf16x8*)(xn + row * DIM + lane * 8) = o;
  }
}

// ---------------- k_gemm_qkv: m97 128x128, [M,640] = xn @ wall^T -----------
// q columns pre-scaled by 0.125*log2(e) so attn uses exp2f(s) directly.
__global__ __launch_bounds__(256) void k_gemm_qkv(
    const bf16* __restrict__ xn, const bf16* __restrict__ wall,
    bf16* __restrict__ qbuf, bf16* __restrict__ kbuf, bf16* __restrict__ vtbuf) {
  __shared__ bf16 sa[2][128 * 32];
  __shared__ bf16 sb[2][128 * 32];
  const int t = threadIdx.x, wave = t >> 6, lane = t & 63;
  const int l15 = lane & 15, g = lane >> 4;
  const int wm = wave >> 1, wn = wave & 1;
  int wg = (blockIdx.x & 7) * 320 + (blockIdx.x >> 3);   // nwg=2560=8*320
  const int bm = wg / 5, bn = wg % 5;
  const char* Abase = (const char*)(xn   + (size_t)bm * 128 * DIM);
  const char* Bbase = (const char*)(wall + (size_t)bn * 128 * DIM);
  const int srow0 = wave * 16 + (lane >> 2);
  const int skb   = (lane & 3) * 16;

  #pragma unroll
  for (int c = 0; c < 2; ++c) {
    int row = c * 64 + srow0;
    int kb = skb ^ ((row & 3) << 4);
    gload_lds16(Abase + (size_t)row * 1024 + kb, (char*)&sa[0][0] + c * 4096 + wave * 1024);
    gload_lds16(Bbase + (size_t)row * 1024 + kb, (char*)&sb[0][0] + c * 4096 + wave * 1024);
  }
  __syncthreads();

  f32x4 acc[4][4];
  #pragma unroll
  for (int mi = 0; mi < 4; ++mi)
    #pragma unroll
    for (int ni = 0; ni < 4; ++ni) acc[mi][ni] = fzero4();

  #pragma unroll 2
  for (int step = 0; step < 16; ++step) {
    const int cur = step & 1;
    if (step < 15) {
      int kk2 = (step + 1) * 64;
      #pragma unroll
      for (int c = 0; c < 2; ++c) {
        int row = c * 64 + srow0;
        int kb = skb ^ ((row & 3) << 4);
        gload_lds16(Abase + (size_t)row * 1024 + kk2 + kb,
                    (char*)&sa[cur ^ 1][0] + c * 4096 + wave * 1024);
        gload_lds16(Bbase + (size_t)row * 1024 + kk2 + kb,
                    (char*)&sb[cur ^ 1][0] + c * 4096 + wave * 1024);
      }
    }
    bf16x8 a[4], b[4];
    #pragma unroll
    for (int mi = 0; mi < 4; ++mi) {
      int row = wm * 64 + mi * 16 + l15;
      a[mi] = *(const bf16x8*)((const char*)&sa[cur][0] + row * 64 + ((g * 16) ^ ((row & 3) << 4)));
    }
    #pragma unroll
    for (int ni = 0; ni < 4; ++ni) {
      int row = wn * 64 + ni * 16 + l15;
      b[ni] = *(const bf16x8*)((const char*)&sb[cur][0] + row * 64 + ((g * 16) ^ ((row & 3) << 4)));
    }
    #pragma unroll
    for (int mi = 0; mi < 4; ++mi)
      #pragma unroll
      for (int ni = 0; ni < 4; ++ni)
        acc[mi][ni] = mfma16(a[mi], b[ni], acc[mi][ni]);
    __syncthreads();
  }

  // epilogue: route cols to q (pre-scaled) / k / vT
  const float QSC = 0.1803368801f;   // 0.125 * log2(e)
  #pragma unroll
  for (int ni = 0; ni < 4; ++ni) {
    int col0 = bn * 128 + wn * 64 + ni * 16;
    if (col0 < 512) {
      bf16* dst = qbuf + col0 + l15;
      #pragma unroll
      for (int mi = 0; mi < 4; ++mi)
        #pragma unroll
        for (int jj = 0; jj < 4; ++jj) {
          size_t row = (size_t)bm * 128 + wm * 64 + mi * 16 + g * 4 + jj;
          dst[row * DIM] = (bf16)(acc[mi][ni][jj] * QSC);
        }
    } else if (col0 < 576) {
      bf16* dst = kbuf + (col0 - 512) + l15;
      #pragma unroll
      for (int mi = 0; mi < 4; ++mi)
        #pragma unroll
        for (int jj = 0; jj < 4; ++jj) {
          size_t row = (size_t)bm * 128 + wm * 64 + mi * 16 + g * 4 + jj;
          dst[row * DHEAD] = (bf16)acc[mi][ni][jj];
        }
    } else {
      // vT[bn_r][d][kv]: jj is kv-contiguous -> packed b64 store
      int d = col0 - 576 + l15;
      #pragma unroll
      for (int mi = 0; mi < 4; ++mi) {
        size_t row = (size_t)bm * 128 + wm * 64 + mi * 16 + g * 4;
        int bnr = (int)(row >> 8), kv = (int)(row & 255);
        bf16x4 v4;
        v4[0] = (bf16)acc[mi][ni][0]; v4[1] = (bf16)acc[mi][ni][1];
        v4[2] = (bf16)acc[mi][ni][2]; v4[3] = (bf16)acc[mi][ni][3];
        *(bf16x4*)(vtbuf + (size_t)bnr * 16384 + (size_t)d * 256 + kv) = v4;
      }
    }
  }
}

// ---------------- k_out_fused: out-proj GEMM (BM=64 x BN=512) + LN -> f32 ---
__global__ __launch_bounds__(512) void k_out_fused(
    const bf16* __restrict__ abuf, const bf16* __restrict__ woutt,
    const float* __restrict__ gout, float* __restrict__ out) {
  __shared__ bf16 sa[2][64 * 32];     // 2 x 4 KB
  __shared__ bf16 sb[2][512 * 32];    // 2 x 32 KB
  __shared__ float2 part[64][4];
  __shared__ float2 stats[64];
  const int t = threadIdx.x, wave = t >> 6, lane = t & 63;
  const int l15 = lane & 15, g = lane >> 4;
  const int wm = wave >> 2, wn = wave & 3;
  int wg = (blockIdx.x & 7) * 128 + (blockIdx.x >> 3);   // nwg=1024=8*128
  const size_t row0 = (size_t)wg * 64;
  const char* Abase = (const char*)(abuf + row0 * DIM);
  const int nsub = wave * 16 + (lane >> 2);
  const int skb  = (lane & 3) * 16;

  #pragma unroll
  for (int c = 0; c < 4; ++c) {
    int row = c * 128 + nsub;
    int kb = skb ^ ((row & 3) << 4);
    gload_lds16((const char*)(woutt + (size_t)row * DIM) + kb,
                (char*)&sb[0][0] + c * 8192 + wave * 1024);
  }
  if (t < 256) {
    int kb = skb ^ ((nsub & 3) << 4);
    gload_lds16(Abase + (size_t)nsub * 1024 + kb,
                (char*)&sa[0][0] + wave * 1024 + (lane & 63) * 16);
  }
  __syncthreads();

  f32x4 acc[2][8];
  #pragma unroll
  for (int mi = 0; mi < 2; ++mi)
    #pragma unroll
    for (int ni = 0; ni < 8; ++ni) acc[mi][ni] = fzero4();

  #pragma unroll 2
  for (int step = 0; step < 16; ++step) {
    const int cur = step & 1;
    if (step < 15) {
      int kk2 = (step + 1) * 64;
      #pragma unroll
      for (int c = 0; c < 4; ++c) {
        int row = c * 128 + nsub;
        int kb = skb ^ ((row & 3) << 4);
        gload_lds16((const char*)(woutt + (size_t)row * DIM) + kk2 + kb,
                    (char*)&sb[cur ^ 1][0] + c * 8192 + wave * 1024);
      }
      if (t < 256) {
        int kb = skb ^ ((nsub & 3) << 4);
        gload_lds16(Abase + (size_t)nsub * 1024 + kk2 + kb,
                    (char*)&sa[cur ^ 1][0] + wave * 1024 + lane * 16);
      }
    }
    bf16x8 a[2];
    #pragma unroll
    for (int mi = 0; mi < 2; ++mi) {
      int row = wm * 32 + mi * 16 + l15;
      a[mi] = *(const bf16x8*)((const char*)&sa[cur][0] + row * 64 + ((g * 16) ^ ((row & 3) << 4)));
    }
    #pragma unroll
    for (int ni = 0; ni < 8; ++ni) {
      int row = wn * 128 + ni * 16 + l15;
      bf16x8 b = *(const bf16x8*)((const char*)&sb[cur][0] + row * 64 + ((g * 16) ^ ((row & 3) << 4)));
      acc[0][ni] = mfma16(a[0], b, acc[0][ni]);
      acc[1][ni] = mfma16(a[1], b, acc[1][ni]);
    }
    __syncthreads();
  }

  #pragma unroll
  for (int mi = 0; mi < 2; ++mi)
    #pragma unroll
    for (int jj = 0; jj < 4; ++jj) {
      float s = 0.f, q = 0.f;
      #pragma unroll
      for (int ni = 0; ni < 8; ++ni) {
        float v = acc[mi][ni][jj];
        s += v; q += v * v;
      }
      s += __shfl_xor(s, 1); q += __shfl_xor(q, 1);
      s += __shfl_xor(s, 2); q += __shfl_xor(q, 2);
      s += __shfl_xor(s, 4); q += __shfl_xor(q, 4);
      s += __shfl_xor(s, 8); q += __shfl_xor(q, 8);
      if (l15 == 0) part[wm * 32 + mi * 16 + g * 4 + jj][wn] = make_float2(s, q);
    }
  __syncthreads();
  if (t < 64) {
    float S = 0.f, Q = 0.f;
    #pragma unroll
    for (int w = 0; w < 4; ++w) { S += part[t][w].x; Q += part[t][w].y; }
    float mean = S * (1.f / 512.f);
    float var  = Q * (1.f / 512.f) - mean * mean;
    stats[t] = make_float2(mean, rsqrtf(var + 1e-5f));
  }
  __syncthreads();

  #pragma unroll
  for (int mi = 0; mi < 2; ++mi)
    #pragma unroll
    for (int ni = 0; ni < 8; ++ni) {
      int col = wn * 128 + ni * 16 + l15;
      float gg = gout[col];
      #pragma unroll
      for (int jj = 0; jj < 4; ++jj) {
        int row = wm * 32 + mi * 16 + g * 4 + jj;
        float2 st = stats[row];
        out[(row0 + row) * DIM + col] = (acc[mi][ni][jj] - st.x) * st.y * gg;
      }
    }
}

// ---------------- k_attn: no-max fused softmax pipeline --------------------
// q arrives PRE-SCALED by 0.125*log2(e) -> p = exp2f(s) directly.
__global__ __launch_bounds__(512, 2) void k_attn(
    bf16* __restrict__ qbuf, const bf16* __restrict__ kbuf,
    const bf16* __restrict__ vtbuf) {
  __shared__ char lds[256 * 144 + 64 * 528];   // lk | lvt, 69 KB
  char* lk  = lds;                  // [kv row][72 bf16] (64 data + 8 pad)
  char* lvt = lds + 256 * 144;      // [d row][264 bf16] (256 data + 8 pad)
  const int t = threadIdx.x, lane = t & 63;
  const int l15 = lane & 15, g = lane >> 4;
  int wg = (blockIdx.x & 7) * 256 + (blockIdx.x >> 3);  // 8 heads/bn per XCD
  const int bn = wg >> 3, h = wg & 7;
  const size_t tok0 = (size_t)bn * RLEN;
  const int m0 = (t >> 6) * 32;

  bf16x8 aq[2][2];
  {
    const bf16* qb = qbuf + (tok0 + m0 + l15) * DIM + h * DHEAD + g * 8;
    #pragma unroll
    for (int qh = 0; qh < 2; ++qh)
      #pragma unroll
      for (int ks = 0; ks < 2; ++ks)
        aq[qh][ks] = *(const bf16x8*)(qb + (size_t)qh * 16 * DIM + ks * 32);
  }
  {
    const bf16* ksrc = kbuf + tok0 * DHEAD;
    const bf16* vsrc = vtbuf + (size_t)bn * (64 * 256);
    bf16x8 kr[4], vr[4];
    #pragma unroll
    for (int i = 0; i < 4; ++i) kr[i] = *(const bf16x8*)(ksrc + (i * 512 + t) * 8);
    #pragma unroll
    for (int i = 0; i < 4; ++i) vr[i] = *(const bf16x8*)(vsrc + (i * 512 + t) * 8);
    #pragma unroll
    for (int i = 0; i < 4; ++i) {
      int off = i * 512 + t;
      *(bf16x8*)(lk + (off >> 3) * 144 + (off & 7) * 16) = kr[i];
    }
    #pragma unroll
    for (int i = 0; i < 4; ++i) {
      int off = i * 512 + t;
      *(bf16x8*)(lvt + (off >> 5) * 528 + (off & 31) * 16) = vr[i];
    }
  }
  __syncthreads();   // single barrier

  const char* bk_base = lk  + l15 * 144 + g * 16;
  const char* bv_base = lvt + l15 * 528 + g * 8;

  f32x4 o2[2][4];
  #pragma unroll
  for (int qh = 0; qh < 2; ++qh)
    #pragma unroll
    for (int di = 0; di < 4; ++di) o2[qh][di] = fzero4();
  float lsum0 = 0.f, lsum1 = 0.f;

  __builtin_amdgcn_s_setprio(1);
  #pragma unroll
  for (int f = 0; f < 16; ++f) {
    bf16x8 bk0 = *(const bf16x8*)(bk_base + f * 2304);
    bf16x8 bk1 = *(const bf16x8*)(bk_base + f * 2304 + 64);
    f32x4 s0 = mfma16(bk0, aq[0][0], fzero4());
    s0 = mfma16(bk1, aq[0][1], s0);
    f32x4 s1 = mfma16(bk0, aq[1][0], fzero4());
    s1 = mfma16(bk1, aq[1][1], s1);
    float p00 = exp2f(s0[0]), p01 = exp2f(s0[1]);
    float p02 = exp2f(s0[2]), p03 = exp2f(s0[3]);
    float p10 = exp2f(s1[0]), p11 = exp2f(s1[1]);
    float p12 = exp2f(s1[2]), p13 = exp2f(s1[3]);
    lsum0 += (p00 + p01) + (p02 + p03);
    lsum1 += (p10 + p11) + (p12 + p13);
    bf16x4 pk0, pk1;
    pk0[0] = (bf16)p00; pk0[1] = (bf16)p01; pk0[2] = (bf16)p02; pk0[3] = (bf16)p03;
    pk1[0] = (bf16)p10; pk1[1] = (bf16)p11; pk1[2] = (bf16)p12; pk1[3] = (bf16)p13;
    #pragma unroll
    for (int di = 0; di < 4; ++di) {
      bf16x4 bv = *(const bf16x4*)(bv_base + di * 8448 + f * 32);
      o2[0][di] = mfma_k16(pk0, bv, o2[0][di]);
      o2[1][di] = mfma_k16(pk1, bv, o2[1][di]);
    }
  }
  __builtin_amdgcn_s_setprio(0);

  float linv[2];
  lsum0 += __shfl_xor(lsum0, 16); lsum0 += __shfl_xor(lsum0, 32);
  lsum1 += __shfl_xor(lsum1, 16); lsum1 += __shfl_xor(lsum1, 32);
  linv[0] = 1.0f / lsum0;
  linv[1] = 1.0f / lsum1;

  #pragma unroll
  for (int qh = 0; qh < 2; ++qh)
    #pragma unroll
    for (int jj = 0; jj < 4; ++jj) {
      float inv = __shfl(linv[qh], 4 * g + jj);
      size_t row = tok0 + m0 + qh * 16 + 4 * g + jj;
      #pragma unroll
      for (int di = 0; di < 4; ++di)
        qbuf[row * DIM + h * DHEAD + di * 16 + l15] = (bf16)(o2[qh][di][jj] * inv);
    }
}

// ---------------- launch ----------------
extern "C" void kernel_launch(void* const* d_in, const int* in_sizes, int n_in,
                              void* d_out, int out_size, void* d_ws, size_t ws_size,
                              hipStream_t stream) {
  const float* x     = (const float*)d_in[0];
  const float* gnorm = (const float*)d_in[1];
  const float* Wq    = (const float*)d_in[2];
  const float* Wkv   = (const float*)d_in[3];
  const float* Wout  = (const float*)d_in[4];
  const float* gout  = (const float*)d_in[5];
  float* out = (float*)d_out;
  char* ws = (char*)d_ws;
  // ws: wall 640K | woutt 512K | xnbuf 64M | qbuf 64M | kbuf 8M | vtbuf 8M
  bf16* wall  = (bf16*)(ws);
  bf16* woutt = (bf16*)(ws + 655360);
  bf16* xnbuf = (bf16*)(ws + 1179648);
  bf16* qbuf  = (bf16*)(ws + 1179648 + (size_t)TOK * DIM * 2);
  bf16* kbuf  = (bf16*)((char*)qbuf + (size_t)TOK * DIM * 2);
  bf16* vtbuf = (bf16*)((char*)kbuf + (size_t)TOK * DHEAD * 2);

  k_prep_ln  <<<dim3(2192), dim3(256), 0, stream>>>(Wq, Wkv, Wout, x, gnorm,
                                                    wall, woutt, xnbuf);
  k_gemm_qkv <<<dim3(2560), dim3(256), 0, stream>>>(xnbuf, wall, qbuf, kbuf, vtbuf);
  k_attn     <<<dim3(2048), dim3(512), 0, stream>>>(qbuf, kbuf, vtbuf);
  k_out_fused<<<dim3(1024), dim3(512), 0, stream>>>(qbuf, woutt, gout, out);
}

// Round 15
// 235.575 us; speedup vs baseline: 1.0755x; 1.0042x over previous
//
#include <hip/hip_runtime.h>
#include <stdint.h>

// Pipeline: k_prep_ln (LDS-transpose weight prep | LN(x)) | k_gemm_qkv
// (m97 128x128, conflict-free swizzle) | k_attn (no-max pipeline, 4 heads/blk)
// | k_out_fused (out-proj + LN).  x[4,64,256,512]; heads=8, dhead=64.

#define DIM   512
#define DHEAD 64
#define RLEN  256
#define TOK   65536
// conflict-free 16B-slot swizzle: lanes 0..7 of a b128 read cover all 32 banks
#define SWZ(row) ((((row) >> 1) & 3) << 4)

typedef __bf16 bf16;
typedef __bf16 bf16x4 __attribute__((ext_vector_type(4)));
typedef __bf16 bf16x8 __attribute__((ext_vector_type(8)));
typedef float  f32x4  __attribute__((ext_vector_type(4)));
typedef short  s16x4  __attribute__((ext_vector_type(4)));

__device__ __forceinline__ f32x4 mfma16(bf16x8 a, bf16x8 b, f32x4 c) {
  return __builtin_amdgcn_mfma_f32_16x16x32_bf16(a, b, c, 0, 0, 0);
}
__device__ __forceinline__ f32x4 mfma_k16(bf16x4 a, bf16x4 b, f32x4 c) {
#if __has_builtin(__builtin_amdgcn_mfma_f32_16x16x16bf16_1k)
  return __builtin_amdgcn_mfma_f32_16x16x16bf16_1k(
      __builtin_bit_cast(s16x4, a), __builtin_bit_cast(s16x4, b), c, 0, 0, 0);
#else
  f32x4 d = c;
  asm volatile("v_mfma_f32_16x16x16_bf16 %0, %1, %2, %0"
               : "+v"(d) : "v"(a), "v"(b));
  return d;
#endif
}
__device__ __forceinline__ f32x4 fzero4() {
  f32x4 z; z[0] = z[1] = z[2] = z[3] = 0.f; return z;
}
__device__ __forceinline__ void gload_lds16(const void* g, void* l) {
  __builtin_amdgcn_global_load_lds(
      (const __attribute__((address_space(1))) void*)g,
      (__attribute__((address_space(3))) void*)l, 16, 0, 0);
}

// ---------------- k_prep_ln ------------------------------------------------
__global__ __launch_bounds__(256) void k_prep_ln(
    const float* __restrict__ Wq, const float* __restrict__ Wkv,
    const float* __restrict__ Wout,
    const float* __restrict__ x, const float* __restrict__ gnorm,
    bf16* __restrict__ wall, bf16* __restrict__ woutt, bf16* __restrict__ xn) {
  if (blockIdx.x < 144) {
    __shared__ bf16 tile[64][72];
    const int b = blockIdx.x, tid = threadIdx.x;
    const float* src; bf16* dst; int srcN, kt, nt;
    if (b < 64)       { src = Wq;   dst = wall;  srcN = 512; kt = b >> 3;        nt = b & 7; }
    else if (b < 128) { src = Wout; dst = woutt; srcN = 512; kt = (b - 64) >> 3; nt = (b - 64) & 7; }
    else              { src = Wkv;  dst = wall + (size_t)512 * DIM; srcN = 128;
                        kt = (b - 128) >> 1; nt = (b - 128) & 1; }
    const int k0 = kt * 64, n0 = nt * 64;
    #pragma unroll
    for (int i = 0; i < 4; ++i) {
      int idx = i * 256 + tid;
      int r = idx >> 4, c4 = (idx & 15) * 4;
      float4 v = *(const float4*)(src + (size_t)(k0 + r) * srcN + n0 + c4);
      tile[r][c4 + 0] = (bf16)v.x;
      tile[r][c4 + 1] = (bf16)v.y;
      tile[r][c4 + 2] = (bf16)v.z;
      tile[r][c4 + 3] = (bf16)v.w;
    }
    __syncthreads();
    #pragma unroll
    for (int i = 0; i < 2; ++i) {
      int idx = i * 256 + tid;
      int n = idx >> 3, c = (idx & 7) * 8;
      bf16x8 o;
      #pragma unroll
      for (int j = 0; j < 8; ++j) o[j] = tile[c + j][n];
      *(bf16x8*)(dst + (size_t)(n0 + n) * DIM + k0 + c) = o;
    }
    return;
  }
  const int lane = threadIdx.x & 63;
  const int gw = (blockIdx.x - 144) * 4 + (threadIdx.x >> 6);
  float gv[8];
  #pragma unroll
  for (int j = 0; j < 8; ++j) gv[j] = gnorm[lane * 8 + j];
  #pragma unroll
  for (int i = 0; i < 8; ++i) {
    size_t row = (size_t)gw * 8 + i;
    const float4* xp = (const float4*)(x + row * DIM + lane * 8);
    float4 v0 = xp[0], v1 = xp[1];
    float s  = v0.x + v0.y + v0.z + v0.w + v1.x + v1.y + v1.z + v1.w;
    float sq = v0.x*v0.x + v0.y*v0.y + v0.z*v0.z + v0.w*v0.w
             + v1.x*v1.x + v1.y*v1.y + v1.z*v1.z + v1.w*v1.w;
    #pragma unroll
    for (int d = 1; d < 64; d <<= 1) { s += __shfl_xor(s, d); sq += __shfl_xor(sq, d); }
    float mean = s * (1.f / 512.f);
    float var  = sq * (1.f / 512.f) - mean * mean;
    float rs   = rsqrtf(var + 1e-5f);
    bf16x8 o;
    o[0] = (bf16)((v0.x - mean) * rs * gv[0]);
    o[1] = (bf16)((v0.y - mean) * rs * gv[1]);
    o[2] = (bf16)((v0.z - mean) * rs * gv[2]);
    o[3] = (bf16)((v0.w - mean) * rs * gv[3]);
    o[4] = (bf16)((v1.x - mean) * rs * gv[4]);
    o[5] = (bf16)((v1.y - mean) * rs * gv[5]);
    o[6] = (bf16)((v1.z - mean) * rs * gv[6]);
    o[7] = (bf16)((v1.w - mean) * rs * gv[7]);
    *(bf16x8*)(xn + row * DIM + lane * 8) = o;
  }
}

// ---------------- k_gemm_qkv: m97 128x128, [M,640] = xn @ wall^T -----------
__global__ __launch_bounds__(256) void k_gemm_qkv(
    const bf16* __restrict__ xn, const bf16* __restrict__ wall,
    bf16* __restrict__ qbuf, bf16* __restrict__ kbuf, bf16* __restrict__ vtbuf) {
  __shared__ bf16 sa[2][128 * 32];
  __shared__ bf16 sb[2][128 * 32];
  const int t = threadIdx.x, wave = t >> 6, lane = t & 63;
  const int l15 = lane & 15, g = lane >> 4;
  const int wm = wave >> 1, wn = wave & 1;
  int wg = (blockIdx.x & 7) * 320 + (blockIdx.x >> 3);   // nwg=2560=8*320
  const int bm = wg / 5, bn = wg % 5;
  const char* Abase = (const char*)(xn   + (size_t)bm * 128 * DIM);
  const char* Bbase = (const char*)(wall + (size_t)bn * 128 * DIM);
  const int srow0 = wave * 16 + (lane >> 2);
  const int skb   = (lane & 3) * 16;

  #pragma unroll
  for (int c = 0; c < 2; ++c) {
    int row = c * 64 + srow0;
    int kb = skb ^ SWZ(row);
    gload_lds16(Abase + (size_t)row * 1024 + kb, (char*)&sa[0][0] + c * 4096 + wave * 1024);
    gload_lds16(Bbase + (size_t)row * 1024 + kb, (char*)&sb[0][0] + c * 4096 + wave * 1024);
  }
  __syncthreads();

  f32x4 acc[4][4];
  #pragma unroll
  for (int mi = 0; mi < 4; ++mi)
    #pragma unroll
    for (int ni = 0; ni < 4; ++ni) acc[mi][ni] = fzero4();

  #pragma unroll 2
  for (int step = 0; step < 16; ++step) {
    const int cur = step & 1;
    if (step < 15) {
      int kk2 = (step + 1) * 64;
      #pragma unroll
      for (int c = 0; c < 2; ++c) {
        int row = c * 64 + srow0;
        int kb = skb ^ SWZ(row);
        gload_lds16(Abase + (size_t)row * 1024 + kk2 + kb,
                    (char*)&sa[cur ^ 1][0] + c * 4096 + wave * 1024);
        gload_lds16(Bbase + (size_t)row * 1024 + kk2 + kb,
                    (char*)&sb[cur ^ 1][0] + c * 4096 + wave * 1024);
      }
    }
    bf16x8 a[4], b[4];
    #pragma unroll
    for (int mi = 0; mi < 4; ++mi) {
      int row = wm * 64 + mi * 16 + l15;
      a[mi] = *(const bf16x8*)((const char*)&sa[cur][0] + row * 64 + ((g * 16) ^ SWZ(row)));
    }
    #pragma unroll
    for (int ni = 0; ni < 4; ++ni) {
      int row = wn * 64 + ni * 16 + l15;
      b[ni] = *(const bf16x8*)((const char*)&sb[cur][0] + row * 64 + ((g * 16) ^ SWZ(row)));
    }
    #pragma unroll
    for (int mi = 0; mi < 4; ++mi)
      #pragma unroll
      for (int ni = 0; ni < 4; ++ni)
        acc[mi][ni] = mfma16(a[mi], b[ni], acc[mi][ni]);
    __syncthreads();
  }

  // epilogue: route cols to q (pre-scaled) / k / vT
  const float QSC = 0.1803368801f;   // 0.125 * log2(e)
  #pragma unroll
  for (int ni = 0; ni < 4; ++ni) {
    int col0 = bn * 128 + wn * 64 + ni * 16;
    if (col0 < 512) {
      bf16* dst = qbuf + col0 + l15;
      #pragma unroll
      for (int mi = 0; mi < 4; ++mi)
        #pragma unroll
        for (int jj = 0; jj < 4; ++jj) {
          size_t row = (size_t)bm * 128 + wm * 64 + mi * 16 + g * 4 + jj;
          dst[row * DIM] = (bf16)(acc[mi][ni][jj] * QSC);
        }
    } else if (col0 < 576) {
      bf16* dst = kbuf + (col0 - 512) + l15;
      #pragma unroll
      for (int mi = 0; mi < 4; ++mi)
        #pragma unroll
        for (int jj = 0; jj < 4; ++jj) {
          size_t row = (size_t)bm * 128 + wm * 64 + mi * 16 + g * 4 + jj;
          dst[row * DHEAD] = (bf16)acc[mi][ni][jj];
        }
    } else {
      // vT[bn_r][d][kv]: jj is kv-contiguous -> packed b64 store
      int d = col0 - 576 + l15;
      #pragma unroll
      for (int mi = 0; mi < 4; ++mi) {
        size_t row = (size_t)bm * 128 + wm * 64 + mi * 16 + g * 4;
        int bnr = (int)(row >> 8), kv = (int)(row & 255);
        bf16x4 v4;
        v4[0] = (bf16)acc[mi][ni][0]; v4[1] = (bf16)acc[mi][ni][1];
        v4[2] = (bf16)acc[mi][ni][2]; v4[3] = (bf16)acc[mi][ni][3];
        *(bf16x4*)(vtbuf + (size_t)bnr * 16384 + (size_t)d * 256 + kv) = v4;
      }
    }
  }
}

// ---------------- k_out_fused: out-proj GEMM (BM=64 x BN=512) + LN -> f32 ---
__global__ __launch_bounds__(512) void k_out_fused(
    const bf16* __restrict__ abuf, const bf16* __restrict__ woutt,
    const float* __restrict__ gout, float* __restrict__ out) {
  __shared__ bf16 sa[2][64 * 32];     // 2 x 4 KB
  __shared__ bf16 sb[2][512 * 32];    // 2 x 32 KB
  __shared__ float2 part[64][4];
  __shared__ float2 stats[64];
  const int t = threadIdx.x, wave = t >> 6, lane = t & 63;
  const int l15 = lane & 15, g = lane >> 4;
  const int wm = wave >> 2, wn = wave & 3;
  int wg = (blockIdx.x & 7) * 128 + (blockIdx.x >> 3);   // nwg=1024=8*128
  const size_t row0 = (size_t)wg * 64;
  const char* Abase = (const char*)(abuf + row0 * DIM);
  const int nsub = wave * 16 + (lane >> 2);
  const int skb  = (lane & 3) * 16;

  #pragma unroll
  for (int c = 0; c < 4; ++c) {
    int row = c * 128 + nsub;
    int kb = skb ^ SWZ(row);
    gload_lds16((const char*)(woutt + (size_t)row * DIM) + kb,
                (char*)&sb[0][0] + c * 8192 + wave * 1024);
  }
  if (t < 256) {
    int kb = skb ^ SWZ(nsub);
    gload_lds16(Abase + (size_t)nsub * 1024 + kb,
                (char*)&sa[0][0] + wave * 1024 + (lane & 63) * 16);
  }
  __syncthreads();

  f32x4 acc[2][8];
  #pragma unroll
  for (int mi = 0; mi < 2; ++mi)
    #pragma unroll
    for (int ni = 0; ni < 8; ++ni) acc[mi][ni] = fzero4();

  #pragma unroll 2
  for (int step = 0; step < 16; ++step) {
    const int cur = step & 1;
    if (step < 15) {
      int kk2 = (step + 1) * 64;
      #pragma unroll
      for (int c = 0; c < 4; ++c) {
        int row = c * 128 + nsub;
        int kb = skb ^ SWZ(row);
        gload_lds16((const char*)(woutt + (size_t)row * DIM) + kk2 + kb,
                    (char*)&sb[cur ^ 1][0] + c * 8192 + wave * 1024);
      }
      if (t < 256) {
        int kb = skb ^ SWZ(nsub);
        gload_lds16(Abase + (size_t)nsub * 1024 + kk2 + kb,
                    (char*)&sa[cur ^ 1][0] + wave * 1024 + lane * 16);
      }
    }
    bf16x8 a[2];
    #pragma unroll
    for (int mi = 0; mi < 2; ++mi) {
      int row = wm * 32 + mi * 16 + l15;
      a[mi] = *(const bf16x8*)((const char*)&sa[cur][0] + row * 64 + ((g * 16) ^ SWZ(row)));
    }
    #pragma unroll
    for (int ni = 0; ni < 8; ++ni) {
      int row = wn * 128 + ni * 16 + l15;
      bf16x8 b = *(const bf16x8*)((const char*)&sb[cur][0] + row * 64 + ((g * 16) ^ SWZ(row)));
      acc[0][ni] = mfma16(a[0], b, acc[0][ni]);
      acc[1][ni] = mfma16(a[1], b, acc[1][ni]);
    }
    __syncthreads();
  }

  #pragma unroll
  for (int mi = 0; mi < 2; ++mi)
    #pragma unroll
    for (int jj = 0; jj < 4; ++jj) {
      float s = 0.f, q = 0.f;
      #pragma unroll
      for (int ni = 0; ni < 8; ++ni) {
        float v = acc[mi][ni][jj];
        s += v; q += v * v;
      }
      s += __shfl_xor(s, 1); q += __shfl_xor(q, 1);
      s += __shfl_xor(s, 2); q += __shfl_xor(q, 2);
      s += __shfl_xor(s, 4); q += __shfl_xor(q, 4);
      s += __shfl_xor(s, 8); q += __shfl_xor(q, 8);
      if (l15 == 0) part[wm * 32 + mi * 16 + g * 4 + jj][wn] = make_float2(s, q);
    }
  __syncthreads();
  if (t < 64) {
    float S = 0.f, Q = 0.f;
    #pragma unroll
    for (int w = 0; w < 4; ++w) { S += part[t][w].x; Q += part[t][w].y; }
    float mean = S * (1.f / 512.f);
    float var  = Q * (1.f / 512.f) - mean * mean;
    stats[t] = make_float2(mean, rsqrtf(var + 1e-5f));
  }
  __syncthreads();

  #pragma unroll
  for (int mi = 0; mi < 2; ++mi)
    #pragma unroll
    for (int ni = 0; ni < 8; ++ni) {
      int col = wn * 128 + ni * 16 + l15;
      float gg = gout[col];
      #pragma unroll
      for (int jj = 0; jj < 4; ++jj) {
        int row = wm * 32 + mi * 16 + g * 4 + jj;
        float2 st = stats[row];
        out[(row0 + row) * DIM + col] = (acc[mi][ni][jj] - st.x) * st.y * gg;
      }
    }
}

// ---------------- k_attn: no-max pipeline, 4 heads per block ---------------
// K and V are shared across heads -> stage once, run 4 heads against them.
// 512 blocks = bn(256) x head-group(2); exactly 2 blocks/CU, one round.
__global__ __launch_bounds__(512, 2) void k_attn(
    bf16* __restrict__ qbuf, const bf16* __restrict__ kbuf,
    const bf16* __restrict__ vtbuf) {
  __shared__ char lds[256 * 144 + 64 * 528];   // lk | lvt, 69 KB
  char* lk  = lds;                  // [kv row][72 bf16] (64 data + 8 pad)
  char* lvt = lds + 256 * 144;      // [d row][264 bf16] (256 data + 8 pad)
  const int t = threadIdx.x, lane = t & 63;
  const int l15 = lane & 15, g = lane >> 4;
  int wg = (blockIdx.x & 7) * 64 + (blockIdx.x >> 3);   // nwg=512=8*64
  const int bn = wg >> 1, h0 = (wg & 1) * 4;
  const size_t tok0 = (size_t)bn * RLEN;
  const int m0 = (t >> 6) * 32;

  // ---- stage K and V^T once (shared by all 4 heads)
  {
    const bf16* ksrc = kbuf + tok0 * DHEAD;
    const bf16* vsrc = vtbuf + (size_t)bn * (64 * 256);
    bf16x8 kr[4], vr[4];
    #pragma unroll
    for (int i = 0; i < 4; ++i) kr[i] = *(const bf16x8*)(ksrc + (i * 512 + t) * 8);
    #pragma unroll
    for (int i = 0; i < 4; ++i) vr[i] = *(const bf16x8*)(vsrc + (i * 512 + t) * 8);
    #pragma unroll
    for (int i = 0; i < 4; ++i) {
      int off = i * 512 + t;
      *(bf16x8*)(lk + (off >> 3) * 144 + (off & 7) * 16) = kr[i];
    }
    #pragma unroll
    for (int i = 0; i < 4; ++i) {
      int off = i * 512 + t;
      *(bf16x8*)(lvt + (off >> 5) * 528 + (off & 31) * 16) = vr[i];
    }
  }
  __syncthreads();   // single barrier

  const char* bk_base = lk  + l15 * 144 + g * 16;
  const char* bv_base = lvt + l15 * 528 + g * 8;
  const bf16* qrow = qbuf + (tok0 + m0 + l15) * DIM + g * 8;

  #pragma unroll
  for (int hi = 0; hi < 4; ++hi) {
    const int h = h0 + hi;
    // Q fragments for this head (L2-hot)
    bf16x8 aq[2][2];
    {
      const bf16* qb = qrow + h * DHEAD;
      #pragma unroll
      for (int qh = 0; qh < 2; ++qh)
        #pragma unroll
        for (int ks = 0; ks < 2; ++ks)
          aq[qh][ks] = *(const bf16x8*)(qb + (size_t)qh * 16 * DIM + ks * 32);
    }

    f32x4 o2[2][4];
    #pragma unroll
    for (int qh = 0; qh < 2; ++qh)
      #pragma unroll
      for (int di = 0; di < 4; ++di) o2[qh][di] = fzero4();
    float lsum0 = 0.f, lsum1 = 0.f;

    __builtin_amdgcn_s_setprio(1);
    #pragma unroll
    for (int f = 0; f < 16; ++f) {
      bf16x8 bk0 = *(const bf16x8*)(bk_base + f * 2304);
      bf16x8 bk1 = *(const bf16x8*)(bk_base + f * 2304 + 64);
      f32x4 s0 = mfma16(bk0, aq[0][0], fzero4());
      s0 = mfma16(bk1, aq[0][1], s0);
      f32x4 s1 = mfma16(bk0, aq[1][0], fzero4());
      s1 = mfma16(bk1, aq[1][1], s1);
      float p00 = exp2f(s0[0]), p01 = exp2f(s0[1]);
      float p02 = exp2f(s0[2]), p03 = exp2f(s0[3]);
      float p10 = exp2f(s1[0]), p11 = exp2f(s1[1]);
      float p12 = exp2f(s1[2]), p13 = exp2f(s1[3]);
      lsum0 += (p00 + p01) + (p02 + p03);
      lsum1 += (p10 + p11) + (p12 + p13);
      bf16x4 pk0, pk1;
      pk0[0] = (bf16)p00; pk0[1] = (bf16)p01; pk0[2] = (bf16)p02; pk0[3] = (bf16)p03;
      pk1[0] = (bf16)p10; pk1[1] = (bf16)p11; pk1[2] = (bf16)p12; pk1[3] = (bf16)p13;
      #pragma unroll
      for (int di = 0; di < 4; ++di) {
        bf16x4 bv = *(const bf16x4*)(bv_base + di * 8448 + f * 32);
        o2[0][di] = mfma_k16(pk0, bv, o2[0][di]);
        o2[1][di] = mfma_k16(pk1, bv, o2[1][di]);
      }
    }
    __builtin_amdgcn_s_setprio(0);

    float linv[2];
    lsum0 += __shfl_xor(lsum0, 16); lsum0 += __shfl_xor(lsum0, 32);
    lsum1 += __shfl_xor(lsum1, 16); lsum1 += __shfl_xor(lsum1, 32);
    linv[0] = 1.0f / lsum0;
    linv[1] = 1.0f / lsum1;

    #pragma unroll
    for (int qh = 0; qh < 2; ++qh)
      #pragma unroll
      for (int jj = 0; jj < 4; ++jj) {
        float inv = __shfl(linv[qh], 4 * g + jj);
        size_t row = tok0 + m0 + qh * 16 + 4 * g + jj;
        #pragma unroll
        for (int di = 0; di < 4; ++di)
          qbuf[row * DIM + h * DHEAD + di * 16 + l15] = (bf16)(o2[qh][di][jj] * inv);
      }
  }
}

// ---------------- launch ----------------
extern "C" void kernel_launch(void* const* d_in, const int* in_sizes, int n_in,
                              void* d_out, int out_size, void* d_ws, size_t ws_size,
                              hipStream_t stream) {
  const float* x     = (const float*)d_in[0];
  const float* gnorm = (const float*)d_in[1];
  const float* Wq    = (const float*)d_in[2];
  const float* Wkv   = (const float*)d_in[3];
  const float* Wout  = (const float*)d_in[4];
  const float* gout  = (const float*)d_in[5];
  float* out = (float*)d_out;
  char* ws = (char*)d_ws;
  // ws: wall 640K | woutt 512K | xnbuf 64M | qbuf 64M | kbuf 8M | vtbuf 8M
  bf16* wall  = (bf16*)(ws);
  bf16* woutt = (bf16*)(ws + 655360);
  bf16* xnbuf = (bf16*)(ws + 1179648);
  bf16* qbuf  = (bf16*)(ws + 1179648 + (size_t)TOK * DIM * 2);
  bf16* kbuf  = (bf16*)((char*)qbuf + (size_t)TOK * DIM * 2);
  bf16* vtbuf = (bf16*)((char*)kbuf + (size_t)TOK * DHEAD * 2);

  k_prep_ln  <<<dim3(2192), dim3(256), 0, stream>>>(Wq, Wkv, Wout, x, gnorm,
                                                    wall, woutt, xnbuf);
  k_gemm_qkv <<<dim3(2560), dim3(256), 0, stream>>>(xnbuf, wall, qbuf, kbuf, vtbuf);
  k_attn     <<<dim3(512),  dim3(512), 0, stream>>>(qbuf, kbuf, vtbuf);
  k_out_fused<<<dim3(1024), dim3(512), 0, stream>>>(qbuf, woutt, gout, out);
}

// Round 16
// 230.391 us; speedup vs baseline: 1.0997x; 1.0225x over previous
//
#include <hip/hip_runtime.h>
#include <stdint.h>

// Pipeline: k_prep_ln (LDS-transpose weight prep | LN(x)) | k_gemm_qkv
// (m97 128x128, conflict-free swizzle) | k_attn (no-max pipeline, 4 heads/blk,
// permuted-QK rows -> K=32 PV) | k_out_fused (out-proj + LN).
// x[4,64,256,512]; heads=8, dhead=64.

#define DIM   512
#define DHEAD 64
#define RLEN  256
#define TOK   65536
// conflict-free 16B-slot swizzle: lanes 0..7 of a b128 read cover all 32 banks
#define SWZ(row) ((((row) >> 1) & 3) << 4)

typedef __bf16 bf16;
typedef __bf16 bf16x4 __attribute__((ext_vector_type(4)));
typedef __bf16 bf16x8 __attribute__((ext_vector_type(8)));
typedef float  f32x4  __attribute__((ext_vector_type(4)));

__device__ __forceinline__ f32x4 mfma16(bf16x8 a, bf16x8 b, f32x4 c) {
  return __builtin_amdgcn_mfma_f32_16x16x32_bf16(a, b, c, 0, 0, 0);
}
__device__ __forceinline__ f32x4 fzero4() {
  f32x4 z; z[0] = z[1] = z[2] = z[3] = 0.f; return z;
}
__device__ __forceinline__ void gload_lds16(const void* g, void* l) {
  __builtin_amdgcn_global_load_lds(
      (const __attribute__((address_space(1))) void*)g,
      (__attribute__((address_space(3))) void*)l, 16, 0, 0);
}

// ---------------- k_prep_ln ------------------------------------------------
__global__ __launch_bounds__(256) void k_prep_ln(
    const float* __restrict__ Wq, const float* __restrict__ Wkv,
    const float* __restrict__ Wout,
    const float* __restrict__ x, const float* __restrict__ gnorm,
    bf16* __restrict__ wall, bf16* __restrict__ woutt, bf16* __restrict__ xn) {
  if (blockIdx.x < 144) {
    __shared__ bf16 tile[64][72];
    const int b = blockIdx.x, tid = threadIdx.x;
    const float* src; bf16* dst; int srcN, kt, nt;
    if (b < 64)       { src = Wq;   dst = wall;  srcN = 512; kt = b >> 3;        nt = b & 7; }
    else if (b < 128) { src = Wout; dst = woutt; srcN = 512; kt = (b - 64) >> 3; nt = (b - 64) & 7; }
    else              { src = Wkv;  dst = wall + (size_t)512 * DIM; srcN = 128;
                        kt = (b - 128) >> 1; nt = (b - 128) & 1; }
    const int k0 = kt * 64, n0 = nt * 64;
    #pragma unroll
    for (int i = 0; i < 4; ++i) {
      int idx = i * 256 + tid;
      int r = idx >> 4, c4 = (idx & 15) * 4;
      float4 v = *(const float4*)(src + (size_t)(k0 + r) * srcN + n0 + c4);
      tile[r][c4 + 0] = (bf16)v.x;
      tile[r][c4 + 1] = (bf16)v.y;
      tile[r][c4 + 2] = (bf16)v.z;
      tile[r][c4 + 3] = (bf16)v.w;
    }
    __syncthreads();
    #pragma unroll
    for (int i = 0; i < 2; ++i) {
      int idx = i * 256 + tid;
      int n = idx >> 3, c = (idx & 7) * 8;
      bf16x8 o;
      #pragma unroll
      for (int j = 0; j < 8; ++j) o[j] = tile[c + j][n];
      *(bf16x8*)(dst + (size_t)(n0 + n) * DIM + k0 + c) = o;
    }
    return;
  }
  const int lane = threadIdx.x & 63;
  const int gw = (blockIdx.x - 144) * 4 + (threadIdx.x >> 6);
  float gv[8];
  #pragma unroll
  for (int j = 0; j < 8; ++j) gv[j] = gnorm[lane * 8 + j];
  #pragma unroll
  for (int i = 0; i < 8; ++i) {
    size_t row = (size_t)gw * 8 + i;
    const float4* xp = (const float4*)(x + row * DIM + lane * 8);
    float4 v0 = xp[0], v1 = xp[1];
    float s  = v0.x + v0.y + v0.z + v0.w + v1.x + v1.y + v1.z + v1.w;
    float sq = v0.x*v0.x + v0.y*v0.y + v0.z*v0.z + v0.w*v0.w
             + v1.x*v1.x + v1.y*v1.y + v1.z*v1.z + v1.w*v1.w;
    #pragma unroll
    for (int d = 1; d < 64; d <<= 1) { s += __shfl_xor(s, d); sq += __shfl_xor(sq, d); }
    float mean = s * (1.f / 512.f);
    float var  = sq * (1.f / 512.f) - mean * mean;
    float rs   = rsqrtf(var + 1e-5f);
    bf16x8 o;
    o[0] = (bf16)((v0.x - mean) * rs * gv[0]);
    o[1] = (bf16)((v0.y - mean) * rs * gv[1]);
    o[2] = (bf16)((v0.z - mean) * rs * gv[2]);
    o[3] = (bf16)((v0.w - mean) * rs * gv[3]);
    o[4] = (bf16)((v1.x - mean) * rs * gv[4]);
    o[5] = (bf16)((v1.y - mean) * rs * gv[5]);
    o[6] = (bf16)((v1.z - mean) * rs * gv[6]);
    o[7] = (bf16)((v1.w - mean) * rs * gv[7]);
    *(bf16x8*)(xn + row * DIM + lane * 8) = o;
  }
}

// ---------------- k_gemm_qkv: m97 128x128, [M,640] = xn @ wall^T -----------
__global__ __launch_bounds__(256) void k_gemm_qkv(
    const bf16* __restrict__ xn, const bf16* __restrict__ wall,
    bf16* __restrict__ qbuf, bf16* __restrict__ kbuf, bf16* __restrict__ vtbuf) {
  __shared__ bf16 sa[2][128 * 32];
  __shared__ bf16 sb[2][128 * 32];
  const int t = threadIdx.x, wave = t >> 6, lane = t & 63;
  const int l15 = lane & 15, g = lane >> 4;
  const int wm = wave >> 1, wn = wave & 1;
  int wg = (blockIdx.x & 7) * 320 + (blockIdx.x >> 3);   // nwg=2560=8*320
  const int bm = wg / 5, bn = wg % 5;
  const char* Abase = (const char*)(xn   + (size_t)bm * 128 * DIM);
  const char* Bbase = (const char*)(wall + (size_t)bn * 128 * DIM);
  const int srow0 = wave * 16 + (lane >> 2);
  const int skb   = (lane & 3) * 16;

  #pragma unroll
  for (int c = 0; c < 2; ++c) {
    int row = c * 64 + srow0;
    int kb = skb ^ SWZ(row);
    gload_lds16(Abase + (size_t)row * 1024 + kb, (char*)&sa[0][0] + c * 4096 + wave * 1024);
    gload_lds16(Bbase + (size_t)row * 1024 + kb, (char*)&sb[0][0] + c * 4096 + wave * 1024);
  }
  __syncthreads();

  f32x4 acc[4][4];
  #pragma unroll
  for (int mi = 0; mi < 4; ++mi)
    #pragma unroll
    for (int ni = 0; ni < 4; ++ni) acc[mi][ni] = fzero4();

  #pragma unroll 2
  for (int step = 0; step < 16; ++step) {
    const int cur = step & 1;
    if (step < 15) {
      int kk2 = (step + 1) * 64;
      #pragma unroll
      for (int c = 0; c < 2; ++c) {
        int row = c * 64 + srow0;
        int kb = skb ^ SWZ(row);
        gload_lds16(Abase + (size_t)row * 1024 + kk2 + kb,
                    (char*)&sa[cur ^ 1][0] + c * 4096 + wave * 1024);
        gload_lds16(Bbase + (size_t)row * 1024 + kk2 + kb,
                    (char*)&sb[cur ^ 1][0] + c * 4096 + wave * 1024);
      }
    }
    bf16x8 a[4], b[4];
    #pragma unroll
    for (int mi = 0; mi < 4; ++mi) {
      int row = wm * 64 + mi * 16 + l15;
      a[mi] = *(const bf16x8*)((const char*)&sa[cur][0] + row * 64 + ((g * 16) ^ SWZ(row)));
    }
    #pragma unroll
    for (int ni = 0; ni < 4; ++ni) {
      int row = wn * 64 + ni * 16 + l15;
      b[ni] = *(const bf16x8*)((const char*)&sb[cur][0] + row * 64 + ((g * 16) ^ SWZ(row)));
    }
    #pragma unroll
    for (int mi = 0; mi < 4; ++mi)
      #pragma unroll
      for (int ni = 0; ni < 4; ++ni)
        acc[mi][ni] = mfma16(a[mi], b[ni], acc[mi][ni]);
    __syncthreads();
  }

  // epilogue: route cols to q (pre-scaled) / k / vT
  const float QSC = 0.1803368801f;   // 0.125 * log2(e)
  #pragma unroll
  for (int ni = 0; ni < 4; ++ni) {
    int col0 = bn * 128 + wn * 64 + ni * 16;
    if (col0 < 512) {
      bf16* dst = qbuf + col0 + l15;
      #pragma unroll
      for (int mi = 0; mi < 4; ++mi)
        #pragma unroll
        for (int jj = 0; jj < 4; ++jj) {
          size_t row = (size_t)bm * 128 + wm * 64 + mi * 16 + g * 4 + jj;
          dst[row * DIM] = (bf16)(acc[mi][ni][jj] * QSC);
        }
    } else if (col0 < 576) {
      bf16* dst = kbuf + (col0 - 512) + l15;
      #pragma unroll
      for (int mi = 0; mi < 4; ++mi)
        #pragma unroll
        for (int jj = 0; jj < 4; ++jj) {
          size_t row = (size_t)bm * 128 + wm * 64 + mi * 16 + g * 4 + jj;
          dst[row * DHEAD] = (bf16)acc[mi][ni][jj];
        }
    } else {
      // vT[bn_r][d][kv]: jj is kv-contiguous -> packed b64 store
      int d = col0 - 576 + l15;
      #pragma unroll
      for (int mi = 0; mi < 4; ++mi) {
        size_t row = (size_t)bm * 128 + wm * 64 + mi * 16 + g * 4;
        int bnr = (int)(row >> 8), kv = (int)(row & 255);
        bf16x4 v4;
        v4[0] = (bf16)acc[mi][ni][0]; v4[1] = (bf16)acc[mi][ni][1];
        v4[2] = (bf16)acc[mi][ni][2]; v4[3] = (bf16)acc[mi][ni][3];
        *(bf16x4*)(vtbuf + (size_t)bnr * 16384 + (size_t)d * 256 + kv) = v4;
      }
    }
  }
}

// ---------------- k_out_fused: out-proj GEMM (BM=64 x BN=512) + LN -> f32 ---
__global__ __launch_bounds__(512) void k_out_fused(
    const bf16* __restrict__ abuf, const bf16* __restrict__ woutt,
    const float* __restrict__ gout, float* __restrict__ out) {
  __shared__ bf16 sa[2][64 * 32];     // 2 x 4 KB
  __shared__ bf16 sb[2][512 * 32];    // 2 x 32 KB
  __shared__ float2 part[64][4];
  __shared__ float2 stats[64];
  const int t = threadIdx.x, wave = t >> 6, lane = t & 63;
  const int l15 = lane & 15, g = lane >> 4;
  const int wm = wave >> 2, wn = wave & 3;
  int wg = (blockIdx.x & 7) * 128 + (blockIdx.x >> 3);   // nwg=1024=8*128
  const size_t row0 = (size_t)wg * 64;
  const char* Abase = (const char*)(abuf + row0 * DIM);
  const int nsub = wave * 16 + (lane >> 2);
  const int skb  = (lane & 3) * 16;

  #pragma unroll
  for (int c = 0; c < 4; ++c) {
    int row = c * 128 + nsub;
    int kb = skb ^ SWZ(row);
    gload_lds16((const char*)(woutt + (size_t)row * DIM) + kb,
                (char*)&sb[0][0] + c * 8192 + wave * 1024);
  }
  if (t < 256) {
    int kb = skb ^ SWZ(nsub);
    gload_lds16(Abase + (size_t)nsub * 1024 + kb,
                (char*)&sa[0][0] + wave * 1024 + (lane & 63) * 16);
  }
  __syncthreads();

  f32x4 acc[2][8];
  #pragma unroll
  for (int mi = 0; mi < 2; ++mi)
    #pragma unroll
    for (int ni = 0; ni < 8; ++ni) acc[mi][ni] = fzero4();

  #pragma unroll 2
  for (int step = 0; step < 16; ++step) {
    const int cur = step & 1;
    if (step < 15) {
      int kk2 = (step + 1) * 64;
      #pragma unroll
      for (int c = 0; c < 4; ++c) {
        int row = c * 128 + nsub;
        int kb = skb ^ SWZ(row);
        gload_lds16((const char*)(woutt + (size_t)row * DIM) + kk2 + kb,
                    (char*)&sb[cur ^ 1][0] + c * 8192 + wave * 1024);
      }
      if (t < 256) {
        int kb = skb ^ SWZ(nsub);
        gload_lds16(Abase + (size_t)nsub * 1024 + kk2 + kb,
                    (char*)&sa[cur ^ 1][0] + wave * 1024 + lane * 16);
      }
    }
    bf16x8 a[2];
    #pragma unroll
    for (int mi = 0; mi < 2; ++mi) {
      int row = wm * 32 + mi * 16 + l15;
      a[mi] = *(const bf16x8*)((const char*)&sa[cur][0] + row * 64 + ((g * 16) ^ SWZ(row)));
    }
    #pragma unroll
    for (int ni = 0; ni < 8; ++ni) {
      int row = wn * 128 + ni * 16 + l15;
      bf16x8 b = *(const bf16x8*)((const char*)&sb[cur][0] + row * 64 + ((g * 16) ^ SWZ(row)));
      acc[0][ni] = mfma16(a[0], b, acc[0][ni]);
      acc[1][ni] = mfma16(a[1], b, acc[1][ni]);
    }
    __syncthreads();
  }

  #pragma unroll
  for (int mi = 0; mi < 2; ++mi)
    #pragma unroll
    for (int jj = 0; jj < 4; ++jj) {
      float s = 0.f, q = 0.f;
      #pragma unroll
      for (int ni = 0; ni < 8; ++ni) {
        float v = acc[mi][ni][jj];
        s += v; q += v * v;
      }
      s += __shfl_xor(s, 1); q += __shfl_xor(q, 1);
      s += __shfl_xor(s, 2); q += __shfl_xor(q, 2);
      s += __shfl_xor(s, 4); q += __shfl_xor(q, 4);
      s += __shfl_xor(s, 8); q += __shfl_xor(q, 8);
      if (l15 == 0) part[wm * 32 + mi * 16 + g * 4 + jj][wn] = make_float2(s, q);
    }
  __syncthreads();
  if (t < 64) {
    float S = 0.f, Q = 0.f;
    #pragma unroll
    for (int w = 0; w < 4; ++w) { S += part[t][w].x; Q += part[t][w].y; }
    float mean = S * (1.f / 512.f);
    float var  = Q * (1.f / 512.f) - mean * mean;
    stats[t] = make_float2(mean, rsqrtf(var + 1e-5f));
  }
  __syncthreads();

  #pragma unroll
  for (int mi = 0; mi < 2; ++mi)
    #pragma unroll
    for (int ni = 0; ni < 8; ++ni) {
      int col = wn * 128 + ni * 16 + l15;
      float gg = gout[col];
      #pragma unroll
      for (int jj = 0; jj < 4; ++jj) {
        int row = wm * 32 + mi * 16 + g * 4 + jj;
        float2 st = stats[row];
        out[(row0 + row) * DIM + col] = (acc[mi][ni][jj] - st.x) * st.y * gg;
      }
    }
}

// ---------------- k_attn: no-max pipeline, 4 heads/blk, K=32 PV ------------
// QK A-rows are PERMUTED so S^T lands directly in the K=32 A-frag layout:
// mfma_a reads K rows kv = 32F + 8*(r>>2) + (r&3), mfma_b the same +4.
// Lane (l15,g) then holds P[q=l15][kv=32F+8g+j] for j=0..7 -> PV runs as
// 64 K=32 MFMAs/head instead of 128 K=16 (half the matrix-pipe issues).
__global__ __launch_bounds__(512, 2) void k_attn(
    bf16* __restrict__ qbuf, const bf16* __restrict__ kbuf,
    const bf16* __restrict__ vtbuf) {
  __shared__ char lds[256 * 144 + 64 * 528];   // lk | lvt, 69 KB
  char* lk  = lds;                  // [kv row][72 bf16] (64 data + 8 pad)
  char* lvt = lds + 256 * 144;      // [d row][264 bf16] (256 data + 8 pad)
  const int t = threadIdx.x, lane = t & 63;
  const int l15 = lane & 15, g = lane >> 4;
  int wg = (blockIdx.x & 7) * 64 + (blockIdx.x >> 3);   // nwg=512=8*64
  const int bn = wg >> 1, h0 = (wg & 1) * 4;
  const size_t tok0 = (size_t)bn * RLEN;
  const int m0 = (t >> 6) * 32;

  // ---- stage K and V^T once (shared by all 4 heads)
  {
    const bf16* ksrc = kbuf + tok0 * DHEAD;
    const bf16* vsrc = vtbuf + (size_t)bn * (64 * 256);
    bf16x8 kr[4], vr[4];
    #pragma unroll
    for (int i = 0; i < 4; ++i) kr[i] = *(const bf16x8*)(ksrc + (i * 512 + t) * 8);
    #pragma unroll
    for (int i = 0; i < 4; ++i) vr[i] = *(const bf16x8*)(vsrc + (i * 512 + t) * 8);
    #pragma unroll
    for (int i = 0; i < 4; ++i) {
      int off = i * 512 + t;
      *(bf16x8*)(lk + (off >> 3) * 144 + (off & 7) * 16) = kr[i];
    }
    #pragma unroll
    for (int i = 0; i < 4; ++i) {
      int off = i * 512 + t;
      *(bf16x8*)(lvt + (off >> 5) * 528 + (off & 31) * 16) = vr[i];
    }
  }
  __syncthreads();   // single barrier

  // permuted K-row base: lane l15 -> kv_local = 8*(l15>>2) + (l15&3)
  const char* bk_a = lk + (8 * (l15 >> 2) + (l15 & 3)) * 144 + g * 16;
  const char* bv_base = lvt + l15 * 528 + g * 16;   // + di*8448 + F*64
  const bf16* qrow = qbuf + (tok0 + m0 + l15) * DIM + g * 8;

  #pragma unroll
  for (int hi = 0; hi < 4; ++hi) {
    const int h = h0 + hi;
    bf16x8 aq[2][2];
    {
      const bf16* qb = qrow + h * DHEAD;
      #pragma unroll
      for (int qh = 0; qh < 2; ++qh)
        #pragma unroll
        for (int ks = 0; ks < 2; ++ks)
          aq[qh][ks] = *(const bf16x8*)(qb + (size_t)qh * 16 * DIM + ks * 32);
    }

    f32x4 o2[2][4];
    #pragma unroll
    for (int qh = 0; qh < 2; ++qh)
      #pragma unroll
      for (int di = 0; di < 4; ++di) o2[qh][di] = fzero4();
    float lsum0 = 0.f, lsum1 = 0.f;

    __builtin_amdgcn_s_setprio(1);
    #pragma unroll
    for (int F = 0; F < 8; ++F) {
      const char* ka = bk_a + F * 4608;
      bf16x8 bk0a = *(const bf16x8*)(ka);
      bf16x8 bk1a = *(const bf16x8*)(ka + 64);
      bf16x8 bk0b = *(const bf16x8*)(ka + 576);
      bf16x8 bk1b = *(const bf16x8*)(ka + 576 + 64);
      f32x4 sa0 = mfma16(bk0a, aq[0][0], fzero4());
      sa0 = mfma16(bk1a, aq[0][1], sa0);
      f32x4 sa1 = mfma16(bk0a, aq[1][0], fzero4());
      sa1 = mfma16(bk1a, aq[1][1], sa1);
      f32x4 sb0 = mfma16(bk0b, aq[0][0], fzero4());
      sb0 = mfma16(bk1b, aq[0][1], sb0);
      f32x4 sb1 = mfma16(bk0b, aq[1][0], fzero4());
      sb1 = mfma16(bk1b, aq[1][1], sb1);
      // exp (q pre-scaled by 0.125*log2e) -> pack K=32 A-frags
      bf16x8 pk0, pk1;
      float e;
      e = exp2f(sa0[0]); lsum0 += e; pk0[0] = (bf16)e;
      e = exp2f(sa0[1]); lsum0 += e; pk0[1] = (bf16)e;
      e = exp2f(sa0[2]); lsum0 += e; pk0[2] = (bf16)e;
      e = exp2f(sa0[3]); lsum0 += e; pk0[3] = (bf16)e;
      e = exp2f(sb0[0]); lsum0 += e; pk0[4] = (bf16)e;
      e = exp2f(sb0[1]); lsum0 += e; pk0[5] = (bf16)e;
      e = exp2f(sb0[2]); lsum0 += e; pk0[6] = (bf16)e;
      e = exp2f(sb0[3]); lsum0 += e; pk0[7] = (bf16)e;
      e = exp2f(sa1[0]); lsum1 += e; pk1[0] = (bf16)e;
      e = exp2f(sa1[1]); lsum1 += e; pk1[1] = (bf16)e;
      e = exp2f(sa1[2]); lsum1 += e; pk1[2] = (bf16)e;
      e = exp2f(sa1[3]); lsum1 += e; pk1[3] = (bf16)e;
      e = exp2f(sb1[0]); lsum1 += e; pk1[4] = (bf16)e;
      e = exp2f(sb1[1]); lsum1 += e; pk1[5] = (bf16)e;
      e = exp2f(sb1[2]); lsum1 += e; pk1[6] = (bf16)e;
      e = exp2f(sb1[3]); lsum1 += e; pk1[7] = (bf16)e;
      // PV: K=32 MFMA, V^T b128 B-frags
      #pragma unroll
      for (int di = 0; di < 4; ++di) {
        bf16x8 bv = *(const bf16x8*)(bv_base + di * 8448 + F * 64);
        o2[0][di] = mfma16(pk0, bv, o2[0][di]);
        o2[1][di] = mfma16(pk1, bv, o2[1][di]);
      }
    }
    __builtin_amdgcn_s_setprio(0);

    float linv[2];
    lsum0 += __shfl_xor(lsum0, 16); lsum0 += __shfl_xor(lsum0, 32);
    lsum1 += __shfl_xor(lsum1, 16); lsum1 += __shfl_xor(lsum1, 32);
    linv[0] = 1.0f / lsum0;
    linv[1] = 1.0f / lsum1;

    #pragma unroll
    for (int qh = 0; qh < 2; ++qh)
      #pragma unroll
      for (int jj = 0; jj < 4; ++jj) {
        float inv = __shfl(linv[qh], 4 * g + jj);
        size_t row = tok0 + m0 + qh * 16 + 4 * g + jj;
        #pragma unroll
        for (int di = 0; di < 4; ++di)
          qbuf[row * DIM + h * DHEAD + di * 16 + l15] = (bf16)(o2[qh][di][jj] * inv);
      }
  }
}

// ---------------- launch ----------------
extern "C" void kernel_launch(void* const* d_in, const int* in_sizes, int n_in,
                              void* d_out, int out_size, void* d_ws, size_t ws_size,
                              hipStream_t stream) {
  const float* x     = (const float*)d_in[0];
  const float* gnorm = (const float*)d_in[1];
  const float* Wq    = (const float*)d_in[2];
  const float* Wkv   = (const float*)d_in[3];
  const float* Wout  = (const float*)d_in[4];
  const float* gout  = (const float*)d_in[5];
  float* out = (float*)d_out;
  char* ws = (char*)d_ws;
  // ws: wall 640K | woutt 512K | xnbuf 64M | qbuf 64M | kbuf 8M | vtbuf 8M
  bf16* wall  = (bf16*)(ws);
  bf16* woutt = (bf16*)(ws + 655360);
  bf16* xnbuf = (bf16*)(ws + 1179648);
  bf16* qbuf  = (bf16*)(ws + 1179648 + (size_t)TOK * DIM * 2);
  bf16* kbuf  = (bf16*)((char*)qbuf + (size_t)TOK * DIM * 2);
  bf16* vtbuf = (bf16*)((char*)kbuf + (size_t)TOK * DHEAD * 2);

  k_prep_ln  <<<dim3(2192), dim3(256), 0, stream>>>(Wq, Wkv, Wout, x, gnorm,
                                                    wall, woutt, xnbuf);
  k_gemm_qkv <<<dim3(2560), dim3(256), 0, stream>>>(xnbuf, wall, qbuf, kbuf, vtbuf);
  k_attn     <<<dim3(512),  dim3(512), 0, stream>>>(qbuf, kbuf, vtbuf);
  k_out_fused<<<dim3(1024), dim3(512), 0, stream>>>(qbuf, woutt, gout, out);
}

// Round 17
// 223.549 us; speedup vs baseline: 1.1334x; 1.0306x over previous
//
#include <hip/hip_runtime.h>
#include <stdint.h>

// Pipeline: k_prep_ln (LDS-transpose weight prep | LN(x)) | k_gemm_qkv
// (128x128, BK=64, 8 barriers) | k_attn (no-max, 4 heads/blk, K=32 PV) |
// k_out_fused (out-proj + LN).  x[4,64,256,512]; heads=8, dhead=64.

#define DIM   512
#define DHEAD 64
#define RLEN  256
#define TOK   65536
// conflict-free 16B-slot swizzle for 4-unit (64B) rows
#define SWZ(row) ((((row) >> 1) & 3) << 4)

typedef __bf16 bf16;
typedef __bf16 bf16x4 __attribute__((ext_vector_type(4)));
typedef __bf16 bf16x8 __attribute__((ext_vector_type(8)));
typedef float  f32x4  __attribute__((ext_vector_type(4)));

__device__ __forceinline__ f32x4 mfma16(bf16x8 a, bf16x8 b, f32x4 c) {
  return __builtin_amdgcn_mfma_f32_16x16x32_bf16(a, b, c, 0, 0, 0);
}
__device__ __forceinline__ f32x4 fzero4() {
  f32x4 z; z[0] = z[1] = z[2] = z[3] = 0.f; return z;
}
__device__ __forceinline__ void gload_lds16(const void* g, void* l) {
  __builtin_amdgcn_global_load_lds(
      (const __attribute__((address_space(1))) void*)g,
      (__attribute__((address_space(3))) void*)l, 16, 0, 0);
}

// ---------------- k_prep_ln ------------------------------------------------
__global__ __launch_bounds__(256) void k_prep_ln(
    const float* __restrict__ Wq, const float* __restrict__ Wkv,
    const float* __restrict__ Wout,
    const float* __restrict__ x, const float* __restrict__ gnorm,
    bf16* __restrict__ wall, bf16* __restrict__ woutt, bf16* __restrict__ xn) {
  if (blockIdx.x < 144) {
    __shared__ bf16 tile[64][72];
    const int b = blockIdx.x, tid = threadIdx.x;
    const float* src; bf16* dst; int srcN, kt, nt;
    if (b < 64)       { src = Wq;   dst = wall;  srcN = 512; kt = b >> 3;        nt = b & 7; }
    else if (b < 128) { src = Wout; dst = woutt; srcN = 512; kt = (b - 64) >> 3; nt = (b - 64) & 7; }
    else              { src = Wkv;  dst = wall + (size_t)512 * DIM; srcN = 128;
                        kt = (b - 128) >> 1; nt = (b - 128) & 1; }
    const int k0 = kt * 64, n0 = nt * 64;
    #pragma unroll
    for (int i = 0; i < 4; ++i) {
      int idx = i * 256 + tid;
      int r = idx >> 4, c4 = (idx & 15) * 4;
      float4 v = *(const float4*)(src + (size_t)(k0 + r) * srcN + n0 + c4);
      tile[r][c4 + 0] = (bf16)v.x;
      tile[r][c4 + 1] = (bf16)v.y;
      tile[r][c4 + 2] = (bf16)v.z;
      tile[r][c4 + 3] = (bf16)v.w;
    }
    __syncthreads();
    #pragma unroll
    for (int i = 0; i < 2; ++i) {
      int idx = i * 256 + tid;
      int n = idx >> 3, c = (idx & 7) * 8;
      bf16x8 o;
      #pragma unroll
      for (int j = 0; j < 8; ++j) o[j] = tile[c + j][n];
      *(bf16x8*)(dst + (size_t)(n0 + n) * DIM + k0 + c) = o;
    }
    return;
  }
  const int lane = threadIdx.x & 63;
  const int gw = (blockIdx.x - 144) * 4 + (threadIdx.x >> 6);
  float gv[8];
  #pragma unroll
  for (int j = 0; j < 8; ++j) gv[j] = gnorm[lane * 8 + j];
  #pragma unroll
  for (int i = 0; i < 8; ++i) {
    size_t row = (size_t)gw * 8 + i;
    const float4* xp = (const float4*)(x + row * DIM + lane * 8);
    float4 v0 = xp[0], v1 = xp[1];
    float s  = v0.x + v0.y + v0.z + v0.w + v1.x + v1.y + v1.z + v1.w;
    float sq = v0.x*v0.x + v0.y*v0.y + v0.z*v0.z + v0.w*v0.w
             + v1.x*v1.x + v1.y*v1.y + v1.z*v1.z + v1.w*v1.w;
    #pragma unroll
    for (int d = 1; d < 64; d <<= 1) { s += __shfl_xor(s, d); sq += __shfl_xor(sq, d); }
    float mean = s * (1.f / 512.f);
    float var  = sq * (1.f / 512.f) - mean * mean;
    float rs   = rsqrtf(var + 1e-5f);
    bf16x8 o;
    o[0] = (bf16)((v0.x - mean) * rs * gv[0]);
    o[1] = (bf16)((v0.y - mean) * rs * gv[1]);
    o[2] = (bf16)((v0.z - mean) * rs * gv[2]);
    o[3] = (bf16)((v0.w - mean) * rs * gv[3]);
    o[4] = (bf16)((v1.x - mean) * rs * gv[4]);
    o[5] = (bf16)((v1.y - mean) * rs * gv[5]);
    o[6] = (bf16)((v1.z - mean) * rs * gv[6]);
    o[7] = (bf16)((v1.w - mean) * rs * gv[7]);
    *(bf16x8*)(xn + row * DIM + lane * 8) = o;
  }
}

// ---------------- k_gemm_qkv: 128x128 tile, BK=64 (8 barriers) -------------
// [M,640] = xn @ wall^T. q cols pre-scaled by 0.125*log2(e).
// LDS rows are 64 bf16 = 8x16B units; unit ^= (row&7) both-sides swizzle.
__global__ __launch_bounds__(256) void k_gemm_qkv(
    const bf16* __restrict__ xn, const bf16* __restrict__ wall,
    bf16* __restrict__ qbuf, bf16* __restrict__ kbuf, bf16* __restrict__ vtbuf) {
  __shared__ bf16 sa[2][128 * 64];   // 2 x 16 KB
  __shared__ bf16 sb[2][128 * 64];   // 2 x 16 KB
  const int t = threadIdx.x, wave = t >> 6, lane = t & 63;
  const int l15 = lane & 15, g = lane >> 4;
  const int wm = wave >> 1, wn = wave & 1;
  int wg = (blockIdx.x & 7) * 320 + (blockIdx.x >> 3);   // nwg=2560=8*320
  const int bm = wg / 5, bn = wg % 5;
  const char* Abase = (const char*)(xn   + (size_t)bm * 128 * DIM);
  const char* Bbase = (const char*)(wall + (size_t)bn * 128 * DIM);

  // prologue: stage K-step 0 (4 chunks per matrix per thread)
  #pragma unroll
  for (int c = 0; c < 4; ++c) {
    int chunk = c * 256 + t;                  // 16B chunks over [128 rows][8 units]
    int row = chunk >> 3, unit = chunk & 7;
    int so = row * 1024 + ((unit ^ (row & 7)) << 4);
    gload_lds16(Abase + so, (char*)&sa[0][0] + c * 4096 + wave * 1024);
    gload_lds16(Bbase + so, (char*)&sb[0][0] + c * 4096 + wave * 1024);
  }
  __syncthreads();

  f32x4 acc[4][4];
  #pragma unroll
  for (int mi = 0; mi < 4; ++mi)
    #pragma unroll
    for (int ni = 0; ni < 4; ++ni) acc[mi][ni] = fzero4();

  for (int step = 0; step < 8; ++step) {
    const int cur = step & 1;
    if (step < 7) {
      int kk2 = (step + 1) * 128;             // byte offset of next k-slab
      #pragma unroll
      for (int c = 0; c < 4; ++c) {
        int chunk = c * 256 + t;
        int row = chunk >> 3, unit = chunk & 7;
        int so = row * 1024 + kk2 + ((unit ^ (row & 7)) << 4);
        gload_lds16(Abase + so, (char*)&sa[cur ^ 1][0] + c * 4096 + wave * 1024);
        gload_lds16(Bbase + so, (char*)&sb[cur ^ 1][0] + c * 4096 + wave * 1024);
      }
    }
    const char* sac = (const char*)&sa[cur][0];
    const char* sbc = (const char*)&sb[cur][0];
    #pragma unroll
    for (int ks = 0; ks < 2; ++ks) {
      bf16x8 a[4], b[4];
      #pragma unroll
      for (int mi = 0; mi < 4; ++mi) {
        int row = wm * 64 + mi * 16 + l15;
        a[mi] = *(const bf16x8*)(sac + row * 128 + (((ks * 4 + g) ^ (row & 7)) << 4));
      }
      #pragma unroll
      for (int ni = 0; ni < 4; ++ni) {
        int row = wn * 64 + ni * 16 + l15;
        b[ni] = *(const bf16x8*)(sbc + row * 128 + (((ks * 4 + g) ^ (row & 7)) << 4));
      }
      #pragma unroll
      for (int mi = 0; mi < 4; ++mi)
        #pragma unroll
        for (int ni = 0; ni < 4; ++ni)
          acc[mi][ni] = mfma16(a[mi], b[ni], acc[mi][ni]);
    }
    __syncthreads();
  }

  // epilogue: route cols to q (pre-scaled) / k / vT
  const float QSC = 0.1803368801f;   // 0.125 * log2(e)
  #pragma unroll
  for (int ni = 0; ni < 4; ++ni) {
    int col0 = bn * 128 + wn * 64 + ni * 16;
    if (col0 < 512) {
      bf16* dst = qbuf + col0 + l15;
      #pragma unroll
      for (int mi = 0; mi < 4; ++mi)
        #pragma unroll
        for (int jj = 0; jj < 4; ++jj) {
          size_t row = (size_t)bm * 128 + wm * 64 + mi * 16 + g * 4 + jj;
          dst[row * DIM] = (bf16)(acc[mi][ni][jj] * QSC);
        }
    } else if (col0 < 576) {
      bf16* dst = kbuf + (col0 - 512) + l15;
      #pragma unroll
      for (int mi = 0; mi < 4; ++mi)
        #pragma unroll
        for (int jj = 0; jj < 4; ++jj) {
          size_t row = (size_t)bm * 128 + wm * 64 + mi * 16 + g * 4 + jj;
          dst[row * DHEAD] = (bf16)acc[mi][ni][jj];
        }
    } else {
      // vT[bn_r][d][kv]: jj is kv-contiguous -> packed b64 store
      int d = col0 - 576 + l15;
      #pragma unroll
      for (int mi = 0; mi < 4; ++mi) {
        size_t row = (size_t)bm * 128 + wm * 64 + mi * 16 + g * 4;
        int bnr = (int)(row >> 8), kv = (int)(row & 255);
        bf16x4 v4;
        v4[0] = (bf16)acc[mi][ni][0]; v4[1] = (bf16)acc[mi][ni][1];
        v4[2] = (bf16)acc[mi][ni][2]; v4[3] = (bf16)acc[mi][ni][3];
        *(bf16x4*)(vtbuf + (size_t)bnr * 16384 + (size_t)d * 256 + kv) = v4;
      }
    }
  }
}

// ---------------- k_out_fused: out-proj GEMM (BM=64 x BN=512) + LN -> f32 ---
__global__ __launch_bounds__(512) void k_out_fused(
    const bf16* __restrict__ abuf, const bf16* __restrict__ woutt,
    const float* __restrict__ gout, float* __restrict__ out) {
  __shared__ bf16 sa[2][64 * 32];     // 2 x 4 KB
  __shared__ bf16 sb[2][512 * 32];    // 2 x 32 KB
  __shared__ float2 part[64][4];
  __shared__ float2 stats[64];
  const int t = threadIdx.x, wave = t >> 6, lane = t & 63;
  const int l15 = lane & 15, g = lane >> 4;
  const int wm = wave >> 2, wn = wave & 3;
  int wg = (blockIdx.x & 7) * 128 + (blockIdx.x >> 3);   // nwg=1024=8*128
  const size_t row0 = (size_t)wg * 64;
  const char* Abase = (const char*)(abuf + row0 * DIM);
  const int nsub = wave * 16 + (lane >> 2);
  const int skb  = (lane & 3) * 16;

  #pragma unroll
  for (int c = 0; c < 4; ++c) {
    int row = c * 128 + nsub;
    int kb = skb ^ SWZ(row);
    gload_lds16((const char*)(woutt + (size_t)row * DIM) + kb,
                (char*)&sb[0][0] + c * 8192 + wave * 1024);
  }
  if (t < 256) {
    int kb = skb ^ SWZ(nsub);
    gload_lds16(Abase + (size_t)nsub * 1024 + kb,
                (char*)&sa[0][0] + wave * 1024 + (lane & 63) * 16);
  }
  __syncthreads();

  f32x4 acc[2][8];
  #pragma unroll
  for (int mi = 0; mi < 2; ++mi)
    #pragma unroll
    for (int ni = 0; ni < 8; ++ni) acc[mi][ni] = fzero4();

  #pragma unroll 2
  for (int step = 0; step < 16; ++step) {
    const int cur = step & 1;
    if (step < 15) {
      int kk2 = (step + 1) * 64;
      #pragma unroll
      for (int c = 0; c < 4; ++c) {
        int row = c * 128 + nsub;
        int kb = skb ^ SWZ(row);
        gload_lds16((const char*)(woutt + (size_t)row * DIM) + kk2 + kb,
                    (char*)&sb[cur ^ 1][0] + c * 8192 + wave * 1024);
      }
      if (t < 256) {
        int kb = skb ^ SWZ(nsub);
        gload_lds16(Abase + (size_t)nsub * 1024 + kk2 + kb,
                    (char*)&sa[cur ^ 1][0] + wave * 1024 + lane * 16);
      }
    }
    bf16x8 a[2];
    #pragma unroll
    for (int mi = 0; mi < 2; ++mi) {
      int row = wm * 32 + mi * 16 + l15;
      a[mi] = *(const bf16x8*)((const char*)&sa[cur][0] + row * 64 + ((g * 16) ^ SWZ(row)));
    }
    #pragma unroll
    for (int ni = 0; ni < 8; ++ni) {
      int row = wn * 128 + ni * 16 + l15;
      bf16x8 b = *(const bf16x8*)((const char*)&sb[cur][0] + row * 64 + ((g * 16) ^ SWZ(row)));
      acc[0][ni] = mfma16(a[0], b, acc[0][ni]);
      acc[1][ni] = mfma16(a[1], b, acc[1][ni]);
    }
    __syncthreads();
  }

  #pragma unroll
  for (int mi = 0; mi < 2; ++mi)
    #pragma unroll
    for (int jj = 0; jj < 4; ++jj) {
      float s = 0.f, q = 0.f;
      #pragma unroll
      for (int ni = 0; ni < 8; ++ni) {
        float v = acc[mi][ni][jj];
        s += v; q += v * v;
      }
      s += __shfl_xor(s, 1); q += __shfl_xor(q, 1);
      s += __shfl_xor(s, 2); q += __shfl_xor(q, 2);
      s += __shfl_xor(s, 4); q += __shfl_xor(q, 4);
      s += __shfl_xor(s, 8); q += __shfl_xor(q, 8);
      if (l15 == 0) part[wm * 32 + mi * 16 + g * 4 + jj][wn] = make_float2(s, q);
    }
  __syncthreads();
  if (t < 64) {
    float S = 0.f, Q = 0.f;
    #pragma unroll
    for (int w = 0; w < 4; ++w) { S += part[t][w].x; Q += part[t][w].y; }
    float mean = S * (1.f / 512.f);
    float var  = Q * (1.f / 512.f) - mean * mean;
    stats[t] = make_float2(mean, rsqrtf(var + 1e-5f));
  }
  __syncthreads();

  #pragma unroll
  for (int mi = 0; mi < 2; ++mi)
    #pragma unroll
    for (int ni = 0; ni < 8; ++ni) {
      int col = wn * 128 + ni * 16 + l15;
      float gg = gout[col];
      #pragma unroll
      for (int jj = 0; jj < 4; ++jj) {
        int row = wm * 32 + mi * 16 + g * 4 + jj;
        float2 st = stats[row];
        out[(row0 + row) * DIM + col] = (acc[mi][ni][jj] - st.x) * st.y * gg;
      }
    }
}

// ---------------- k_attn: no-max pipeline, 4 heads/blk, K=32 PV ------------
__global__ __launch_bounds__(512, 2) void k_attn(
    bf16* __restrict__ qbuf, const bf16* __restrict__ kbuf,
    const bf16* __restrict__ vtbuf) {
  __shared__ char lds[256 * 144 + 64 * 528];   // lk | lvt, 69 KB
  char* lk  = lds;                  // [kv row][72 bf16] (64 data + 8 pad)
  char* lvt = lds + 256 * 144;      // [d row][264 bf16] (256 data + 8 pad)
  const int t = threadIdx.x, lane = t & 63;
  const int l15 = lane & 15, g = lane >> 4;
  int wg = (blockIdx.x & 7) * 64 + (blockIdx.x >> 3);   // nwg=512=8*64
  const int bn = wg >> 1, h0 = (wg & 1) * 4;
  const size_t tok0 = (size_t)bn * RLEN;
  const int m0 = (t >> 6) * 32;

  // ---- stage K and V^T once (shared by all 4 heads)
  {
    const bf16* ksrc = kbuf + tok0 * DHEAD;
    const bf16* vsrc = vtbuf + (size_t)bn * (64 * 256);
    bf16x8 kr[4], vr[4];
    #pragma unroll
    for (int i = 0; i < 4; ++i) kr[i] = *(const bf16x8*)(ksrc + (i * 512 + t) * 8);
    #pragma unroll
    for (int i = 0; i < 4; ++i) vr[i] = *(const bf16x8*)(vsrc + (i * 512 + t) * 8);
    #pragma unroll
    for (int i = 0; i < 4; ++i) {
      int off = i * 512 + t;
      *(bf16x8*)(lk + (off >> 3) * 144 + (off & 7) * 16) = kr[i];
    }
    #pragma unroll
    for (int i = 0; i < 4; ++i) {
      int off = i * 512 + t;
      *(bf16x8*)(lvt + (off >> 5) * 528 + (off & 31) * 16) = vr[i];
    }
  }
  __syncthreads();   // single barrier

  // permuted K-row base: lane l15 -> kv_local = 8*(l15>>2) + (l15&3)
  const char* bk_a = lk + (8 * (l15 >> 2) + (l15 & 3)) * 144 + g * 16;
  const char* bv_base = lvt + l15 * 528 + g * 16;   // + di*8448 + F*64
  const bf16* qrow = qbuf + (tok0 + m0 + l15) * DIM + g * 8;

  #pragma unroll
  for (int hi = 0; hi < 4; ++hi) {
    const int h = h0 + hi;
    bf16x8 aq[2][2];
    {
      const bf16* qb = qrow + h * DHEAD;
      #pragma unroll
      for (int qh = 0; qh < 2; ++qh)
        #pragma unroll
        for (int ks = 0; ks < 2; ++ks)
          aq[qh][ks] = *(const bf16x8*)(qb + (size_t)qh * 16 * DIM + ks * 32);
    }

    f32x4 o2[2][4];
    #pragma unroll
    for (int qh = 0; qh < 2; ++qh)
      #pragma unroll
      for (int di = 0; di < 4; ++di) o2[qh][di] = fzero4();
    float lsum0 = 0.f, lsum1 = 0.f;

    __builtin_amdgcn_s_setprio(1);
    #pragma unroll
    for (int F = 0; F < 8; ++F) {
      const char* ka = bk_a + F * 4608;
      bf16x8 bk0a = *(const bf16x8*)(ka);
      bf16x8 bk1a = *(const bf16x8*)(ka + 64);
      bf16x8 bk0b = *(const bf16x8*)(ka + 576);
      bf16x8 bk1b = *(const bf16x8*)(ka + 576 + 64);
      f32x4 sa0 = mfma16(bk0a, aq[0][0], fzero4());
      sa0 = mfma16(bk1a, aq[0][1], sa0);
      f32x4 sa1 = mfma16(bk0a, aq[1][0], fzero4());
      sa1 = mfma16(bk1a, aq[1][1], sa1);
      f32x4 sb0 = mfma16(bk0b, aq[0][0], fzero4());
      sb0 = mfma16(bk1b, aq[0][1], sb0);
      f32x4 sb1 = mfma16(bk0b, aq[1][0], fzero4());
      sb1 = mfma16(bk1b, aq[1][1], sb1);
      bf16x8 pk0, pk1;
      float e;
      e = exp2f(sa0[0]); lsum0 += e; pk0[0] = (bf16)e;
      e = exp2f(sa0[1]); lsum0 += e; pk0[1] = (bf16)e;
      e = exp2f(sa0[2]); lsum0 += e; pk0[2] = (bf16)e;
      e = exp2f(sa0[3]); lsum0 += e; pk0[3] = (bf16)e;
      e = exp2f(sb0[0]); lsum0 += e; pk0[4] = (bf16)e;
      e = exp2f(sb0[1]); lsum0 += e; pk0[5] = (bf16)e;
      e = exp2f(sb0[2]); lsum0 += e; pk0[6] = (bf16)e;
      e = exp2f(sb0[3]); lsum0 += e; pk0[7] = (bf16)e;
      e = exp2f(sa1[0]); lsum1 += e; pk1[0] = (bf16)e;
      e = exp2f(sa1[1]); lsum1 += e; pk1[1] = (bf16)e;
      e = exp2f(sa1[2]); lsum1 += e; pk1[2] = (bf16)e;
      e = exp2f(sa1[3]); lsum1 += e; pk1[3] = (bf16)e;
      e = exp2f(sb1[0]); lsum1 += e; pk1[4] = (bf16)e;
      e = exp2f(sb1[1]); lsum1 += e; pk1[5] = (bf16)e;
      e = exp2f(sb1[2]); lsum1 += e; pk1[6] = (bf16)e;
      e = exp2f(sb1[3]); lsum1 += e; pk1[7] = (bf16)e;
      #pragma unroll
      for (int di = 0; di < 4; ++di) {
        bf16x8 bv = *(const bf16x8*)(bv_base + di * 8448 + F * 64);
        o2[0][di] = mfma16(pk0, bv, o2[0][di]);
        o2[1][di] = mfma16(pk1, bv, o2[1][di]);
      }
    }
    __builtin_amdgcn_s_setprio(0);

    float linv[2];
    lsum0 += __shfl_xor(lsum0, 16); lsum0 += __shfl_xor(lsum0, 32);
    lsum1 += __shfl_xor(lsum1, 16); lsum1 += __shfl_xor(lsum1, 32);
    linv[0] = 1.0f / lsum0;
    linv[1] = 1.0f / lsum1;

    #pragma unroll
    for (int qh = 0; qh < 2; ++qh)
      #pragma unroll
      for (int jj = 0; jj < 4; ++jj) {
        float inv = __shfl(linv[qh], 4 * g + jj);
        size_t row = tok0 + m0 + qh * 16 + 4 * g + jj;
        #pragma unroll
        for (int di = 0; di < 4; ++di)
          qbuf[row * DIM + h * DHEAD + di * 16 + l15] = (bf16)(o2[qh][di][jj] * inv);
      }
  }
}

// ---------------- launch ----------------
extern "C" void kernel_launch(void* const* d_in, const int* in_sizes, int n_in,
                              void* d_out, int out_size, void* d_ws, size_t ws_size,
                              hipStream_t stream) {
  const float* x     = (const float*)d_in[0];
  const float* gnorm = (const float*)d_in[1];
  const float* Wq    = (const float*)d_in[2];
  const float* Wkv   = (const float*)d_in[3];
  const float* Wout  = (const float*)d_in[4];
  const float* gout  = (const float*)d_in[5];
  float* out = (float*)d_out;
  char* ws = (char*)d_ws;
  // ws: wall 640K | woutt 512K | xnbuf 64M | qbuf 64M | kbuf 8M | vtbuf 8M
  bf16* wall  = (bf16*)(ws);
  bf16* woutt = (bf16*)(ws + 655360);
  bf16* xnbuf = (bf16*)(ws + 1179648);
  bf16* qbuf  = (bf16*)(ws + 1179648 + (size_t)TOK * DIM * 2);
  bf16* kbuf  = (bf16*)((char*)qbuf + (size_t)TOK * DIM * 2);
  bf16* vtbuf = (bf16*)((char*)kbuf + (size_t)TOK * DHEAD * 2);

  k_prep_ln  <<<dim3(2192), dim3(256), 0, stream>>>(Wq, Wkv, Wout, x, gnorm,
                                                    wall, woutt, xnbuf);
  k_gemm_qkv <<<dim3(2560), dim3(256), 0, stream>>>(xnbuf, wall, qbuf, kbuf, vtbuf);
  k_attn     <<<dim3(512),  dim3(512), 0, stream>>>(qbuf, kbuf, vtbuf);
  k_out_fused<<<dim3(1024), dim3(512), 0, stream>>>(qbuf, woutt, gout, out);
}